// Round 2
// baseline (306.056 us; speedup 1.0000x reference)
//
#include <hip/hip_runtime.h>
#include <math.h>

#define S_DIM 8
#define N_RES 256
#define MSA_DIM 256
#define PAIR_DIM 128
#define D_DIM 32
#define H_DIM 8
#define M_ROWS (S_DIM * N_RES)      // 2048
#define QKV_N (3 * H_DIM * D_DIM)   // 768
#define HD (H_DIM * D_DIM)          // 256
#define XW_N 1024                   // qkv(768) + gate(256)
#define LOG2E 1.4426950408889634f
#define GRID_BLKS 512

typedef __attribute__((ext_vector_type(8))) short short8;
typedef __attribute__((ext_vector_type(4))) float floatx4;

// ---- wave64 sum via DPP; total lands in lane 63
#define DPP_ADD(x, ctrl, rmask)                                                \
    x += __int_as_float(__builtin_amdgcn_update_dpp(                           \
        0, __float_as_int(x), (ctrl), (rmask), 0xf, true))

__device__ __forceinline__ float wave_sum63(float x) {
    DPP_ADD(x, 0x111, 0xf);
    DPP_ADD(x, 0x112, 0xf);
    DPP_ADD(x, 0x114, 0xf);
    DPP_ADD(x, 0x118, 0xf);
    DPP_ADD(x, 0x142, 0xa);
    DPP_ADD(x, 0x143, 0xc);
    return x;
}

__device__ __forceinline__ float quad_sum(float x) {
    x += __int_as_float(__builtin_amdgcn_update_dpp(
        0, __float_as_int(x), 0xB1, 0xf, 0xf, true));
    x += __int_as_float(__builtin_amdgcn_update_dpp(
        0, __float_as_int(x), 0x4E, 0xf, 0xf, true));
    return x;
}

__device__ __forceinline__ unsigned short bf16rn(float v) {
    unsigned u = __float_as_uint(v);
    return (unsigned short)((u + 0x7FFF + ((u >> 16) & 1)) >> 16);
}

// ---- grid-wide sense-reversing barrier (cross-XCD safe) -------------------
// State lives in __device__ globals (NOT workspace -> immune to ws poison).
// Protocol is self-restoring across graph replays: g_count returns to 0 after
// every barrier; g_sense persists and every block reads it at kernel entry
// (provably before any block can complete barrier #1, since completion needs
// all 512 arrivals). Deadlock-free: 64KiB LDS/block + launch_bounds(256,2)
// guarantee 2 blocks/CU * 256 CUs = 512 co-resident blocks.
__device__ unsigned g_count = 0;
__device__ unsigned g_sense = 0;

__device__ __forceinline__ void grid_sync(unsigned& lsense) {
    __syncthreads();
    lsense ^= 1u;
    if (threadIdx.x == 0) {
        __threadfence();  // release: publish this block's writes (L2 wb)
        unsigned old = atomicAdd(&g_count, 1u);
        if (old == GRID_BLKS - 1) {
            __hip_atomic_store(&g_count, 0u, __ATOMIC_RELAXED,
                               __HIP_MEMORY_SCOPE_AGENT);
            __hip_atomic_store(&g_sense, lsense, __ATOMIC_RELEASE,
                               __HIP_MEMORY_SCOPE_AGENT);
        } else {
            while (__hip_atomic_load(&g_sense, __ATOMIC_RELAXED,
                                     __HIP_MEMORY_SCOPE_AGENT) != lsense)
                __builtin_amdgcn_s_sleep(2);
        }
        __threadfence();  // acquire: invalidate stale L1/L2 lines
    }
    __syncthreads();
}

// ==================== single fused persistent kernel =======================
// stage 0: LN(msa)->xhi/xlo ; wconv(w_qkv|w_g) ; wconv(w_out, perm)
// stage 1: role split per CU: even blocks xw-GEMM (2 tiles 64x64),
//          odd blocks pair_bias (4 units of 64 rows)
// stage 2: attention (1 unit/block, K/V in LDS)
// stage 3: out projection (1 tile 16x64 per block)
__global__ __launch_bounds__(256, 2) void fused_kernel(
    const float* __restrict__ msa, const float* __restrict__ lnw,
    const float* __restrict__ lnb,
    const float* __restrict__ w_qkv, const float* __restrict__ w_g,
    const float* __restrict__ w_out,
    const float* __restrict__ pair, const float* __restrict__ plw,
    const float* __restrict__ plb, const float* __restrict__ wb,
    const float* __restrict__ b_out, float* __restrict__ out,
    float* __restrict__ q_t, float* __restrict__ k_t,
    float* __restrict__ v_t, float* __restrict__ g_t,
    float* __restrict__ b2,
    unsigned short* __restrict__ xhi, unsigned short* __restrict__ xlo,
    unsigned short* __restrict__ whiT, unsigned short* __restrict__ wloT,
    unsigned short* __restrict__ wouthiT, unsigned short* __restrict__ woutloT,
    unsigned short* __restrict__ ao_hi, unsigned short* __restrict__ ao_lo)
{
    __shared__ __align__(16) char smem[65536];
    int b = blockIdx.x;
    int t = threadIdx.x;
    unsigned lsense = __hip_atomic_load(&g_sense, __ATOMIC_RELAXED,
                                        __HIP_MEMORY_SCOPE_AGENT);

    // ---------------- stage 0: LN(msa) + weight conversions ----------------
    {
        // LayerNorm: one wave per row, 4 rows/block
        int wv = t >> 6, l = t & 63;
        int row = b * 4 + wv;
        float4 v4 = *(const float4*)&msa[(size_t)row * 256 + l * 4];
        float s1 = v4.x + v4.y + v4.z + v4.w;
        float s2 = v4.x * v4.x + v4.y * v4.y + v4.z * v4.z + v4.w * v4.w;
        s1 = wave_sum63(s1);
        s2 = wave_sum63(s2);
        float S1 = __int_as_float(__builtin_amdgcn_readlane(__float_as_int(s1), 63));
        float S2 = __int_as_float(__builtin_amdgcn_readlane(__float_as_int(s2), 63));
        float mu = S1 * (1.0f / 256.0f);
        float var = S2 * (1.0f / 256.0f) - mu * mu;
        float rs = rsqrtf(var + 1e-5f);
        float4 w4 = *(const float4*)&lnw[l * 4];
        float4 bb4 = *(const float4*)&lnb[l * 4];
        float y[4];
        y[0] = (v4.x - mu) * rs * w4.x + bb4.x;
        y[1] = (v4.y - mu) * rs * w4.y + bb4.y;
        y[2] = (v4.z - mu) * rs * w4.z + bb4.z;
        y[3] = (v4.w - mu) * rs * w4.w + bb4.w;
        unsigned short hh[4], ll[4];
#pragma unroll
        for (int i = 0; i < 4; i++) {
            hh[i] = bf16rn(y[i]);
            ll[i] = bf16rn(y[i] - __uint_as_float((unsigned)hh[i] << 16));
        }
        uint2 ph, pl;
        ph.x = (unsigned)hh[0] | ((unsigned)hh[1] << 16);
        ph.y = (unsigned)hh[2] | ((unsigned)hh[3] << 16);
        pl.x = (unsigned)ll[0] | ((unsigned)ll[1] << 16);
        pl.y = (unsigned)ll[2] | ((unsigned)ll[3] << 16);
        *(uint2*)&xhi[(size_t)row * 256 + l * 4] = ph;
        *(uint2*)&xlo[(size_t)row * 256 + l * 4] = pl;

        // wconv W = [w_qkv | w_g]: 32768 units = 512 blocks * 64
        if (t < 64) {
            int id = b * 64 + t;
            int n = id >> 5, oct = id & 31, k0 = oct * 8;
            const float* src;
            int stride;
            if (n < QKV_N) { src = w_qkv + n; stride = QKV_N; }
            else           { src = w_g + (n - QKV_N); stride = HD; }
            unsigned short h8[8], l8[8];
#pragma unroll
            for (int j = 0; j < 8; j++) {
                float v = src[(size_t)(k0 + j) * stride];
                unsigned short h = bf16rn(v);
                h8[j] = h;
                l8[j] = bf16rn(v - __uint_as_float((unsigned)h << 16));
            }
            *(short8*)&whiT[n * 256 + k0] = *(short8*)h8;
            *(short8*)&wloT[n * 256 + k0] = *(short8*)l8;
        } else if (t < 80) {
            // wconv w_out (ao-layout row perm): 8192 units = 512 * 16
            int id = b * 16 + (t - 64);
            int n = id >> 5, oct = id & 31, k0 = oct * 8;
            unsigned short h8[8], l8[8];
#pragma unroll
            for (int j = 0; j < 8; j++) {
                int k = k0 + j;
                int wrow = (k & 31) * 8 + (k >> 5);
                float v = w_out[(size_t)wrow * 256 + n];
                unsigned short h = bf16rn(v);
                h8[j] = h;
                l8[j] = bf16rn(v - __uint_as_float((unsigned)h << 16));
            }
            *(short8*)&wouthiT[n * 256 + k0] = *(short8*)h8;
            *(short8*)&woutloT[n * 256 + k0] = *(short8*)l8;
        }
    }
    grid_sync(lsense);

    // ------- stage 1: even blocks = xw GEMM (2 tiles), odd = pair_bias -----
    if ((b & 1) == 0) {
        unsigned short* As = (unsigned short*)smem;          // 64*72*2 = 9216
        unsigned short* Bs = As + 64 * 72;                   // 9216
        float* Cs = (float*)(smem + 18432);                  // 64*68*4 = 17408
        int w = t >> 6, L = t & 63;
        int wm = (w & 1) * 32, wn = (w >> 1) * 32;
        int l15 = L & 15, l4 = L >> 4;
        int alm = t >> 3, alk = (t & 7) * 8;
        for (int tt = 0; tt < 2; tt++) {
            int tile = (b >> 1) * 2 + tt;
            int n0 = (tile & 15) * 64, m0 = (tile >> 4) * 64;
            floatx4 acc[2][2];
#pragma unroll
            for (int a = 0; a < 2; a++)
#pragma unroll
                for (int c = 0; c < 2; c++) acc[a][c] = (floatx4){0, 0, 0, 0};

            short8 pa0 = *(const short8*)&xhi[(m0 + alm) * 256 + alk];
            short8 pa1 = *(const short8*)&xhi[(m0 + alm + 32) * 256 + alk];
            short8 pb[2];
#pragma unroll
            for (int j = 0; j < 2; j++) {
                int id = t + 256 * j;
                int bn = id >> 3, bc = (id & 7) * 8;
                pb[j] = *(const short8*)&whiT[(n0 + bn) * 256 + bc];
            }
            for (int r = 0; r < 12; r++) {
                __syncthreads();
                *(short8*)&As[alm * 72 + alk] = pa0;
                *(short8*)&As[(alm + 32) * 72 + alk] = pa1;
#pragma unroll
                for (int j = 0; j < 2; j++) {
                    int id = t + 256 * j;
                    int bn = id >> 3, bc = (id & 7) * 8;
                    *(short8*)&Bs[bn * 72 + bc] = pb[j];
                }
                __syncthreads();
                if (r < 11) {
                    int rn = r + 1;
                    int seg = rn >> 2, kb = (rn & 3) * 64;
                    const unsigned short* An = (seg == 1) ? xlo : xhi;
                    const unsigned short* Bn = (seg == 2) ? wloT : whiT;
                    pa0 = *(const short8*)&An[(m0 + alm) * 256 + kb + alk];
                    pa1 = *(const short8*)&An[(m0 + alm + 32) * 256 + kb + alk];
#pragma unroll
                    for (int j = 0; j < 2; j++) {
                        int id = t + 256 * j;
                        int bn = id >> 3, bc = (id & 7) * 8;
                        pb[j] = *(const short8*)&Bn[(n0 + bn) * 256 + kb + bc];
                    }
                }
#pragma unroll
                for (int ks = 0; ks < 2; ks++) {
                    int ko = ks * 32 + l4 * 8;
                    short8 af[2], bf[2];
#pragma unroll
                    for (int a = 0; a < 2; a++)
                        af[a] = *(short8*)&As[(wm + a * 16 + l15) * 72 + ko];
#pragma unroll
                    for (int c = 0; c < 2; c++)
                        bf[c] = *(short8*)&Bs[(wn + c * 16 + l15) * 72 + ko];
#pragma unroll
                    for (int a = 0; a < 2; a++)
#pragma unroll
                        for (int c = 0; c < 2; c++)
                            acc[a][c] = __builtin_amdgcn_mfma_f32_16x16x32_bf16(
                                af[a], bf[c], acc[a][c], 0, 0, 0);
                }
            }
#pragma unroll
            for (int a = 0; a < 2; a++)
#pragma unroll
                for (int c = 0; c < 2; c++) {
                    int nl = wn + c * 16 + l15;
#pragma unroll
                    for (int rg = 0; rg < 4; rg++) {
                        int ml = wm + a * 16 + l4 * 4 + rg;
                        Cs[ml * 68 + nl] = acc[a][c][rg];
                    }
                }
            __syncthreads();
            int qkv_mode = (n0 < QKV_N);
            int chunk = n0 >> 8;
            int dbase = (n0 & 255) >> 3;
#pragma unroll
            for (int j = 0; j < 4; j++) {
                int id = t + 256 * j;
                int m = id >> 4;
                int h = (id >> 1) & 7;
                int dq = id & 1;
                float vals[4];
#pragma unroll
                for (int jj = 0; jj < 4; jj++)
                    vals[jj] = Cs[m * 68 + (dq * 4 + jj) * 8 + h];
                int mm = m0 + m;
                int daddr = dbase + dq * 4;
                if (qkv_mode) {
                    float* dst = (chunk == 0) ? q_t : ((chunk == 1) ? k_t : v_t);
                    *(float4*)&dst[(size_t)(h * M_ROWS + mm) * D_DIM + daddr] =
                        *(float4*)vals;
                } else {
                    float4 o;
                    o.x = 1.0f / (1.0f + __expf(-vals[0]));
                    o.y = 1.0f / (1.0f + __expf(-vals[1]));
                    o.z = 1.0f / (1.0f + __expf(-vals[2]));
                    o.w = 1.0f / (1.0f + __expf(-vals[3]));
                    *(float4*)&g_t[(size_t)(h * M_ROWS + mm) * D_DIM + daddr] = o;
                }
            }
            __syncthreads();
        }
    } else {
        // ---------------- pair_bias: 4 units of 64 rows ----------------
        float* As = (float*)smem;
        float* Spart = (float*)smem + 1552;
        float* Qpart = (float*)smem + 1816;
        if (t < 128) {
            float lwc = plw[t];
#pragma unroll
            for (int h = 0; h < 8; h++)
                As[t * 12 + h] = lwc * wb[t * 8 + h] * LOG2E;
        }
        __syncthreads();
        {
            int h = t >> 5, seg = t & 31, cbase = seg * 4;
            float sa = 0, sq = 0;
#pragma unroll
            for (int cc = 0; cc < 4; cc++) {
                int c = cbase + cc;
                sa += As[c * 12 + h];
                sq += plb[c] * wb[c * 8 + h];
            }
            Spart[h * 33 + seg] = sa;
            Qpart[h * 33 + seg] = sq * LOG2E;
        }
        __syncthreads();
        if (t < 8) {
            float s = 0, q = 0;
#pragma unroll
            for (int j = 0; j < 32; j++) {
                s += Spart[t * 33 + j];
                q += Qpart[t * 33 + j];
            }
            As[1536 + t] = s;
            As[1544 + t] = q;
        }
        __syncthreads();
        for (int u4 = 0; u4 < 4; u4++) {
            int unit = (b >> 1) * 4 + u4;      // [0,1024)
            int row = unit * 64 + (t >> 2);
            int q = t & 3;
            const float* in = pair + (size_t)row * PAIR_DIM;
            float4 x4[8];
#pragma unroll
            for (int it = 0; it < 8; it++)
                x4[it] = *(const float4*)&in[it * 16 + q * 4];
            float s = 0, s2 = 0;
            float dot[8] = {};
#pragma unroll
            for (int it = 0; it < 8; it++) {
                float xk[4];
                *(float4*)xk = x4[it];
#pragma unroll
                for (int k = 0; k < 4; k++) {
                    int c = it * 16 + q * 4 + k;
                    float xv = xk[k];
                    s += xv; s2 += xv * xv;
                    float4 A0 = *(const float4*)&As[c * 12];
                    float4 A1 = *(const float4*)&As[c * 12 + 4];
                    dot[0] += xv * A0.x; dot[1] += xv * A0.y;
                    dot[2] += xv * A0.z; dot[3] += xv * A0.w;
                    dot[4] += xv * A1.x; dot[5] += xv * A1.y;
                    dot[6] += xv * A1.z; dot[7] += xv * A1.w;
                }
            }
            s = quad_sum(s);
            s2 = quad_sum(s2);
#pragma unroll
            for (int h = 0; h < 8; h++) dot[h] = quad_sum(dot[h]);
            float mu = s * (1.0f / 128.0f);
            float var = s2 * (1.0f / 128.0f) - mu * mu;
            float rs = rsqrtf(var + 1e-5f);
            int h0 = q * 2;
#pragma unroll
            for (int u = 0; u < 2; u++) {
                int h = h0 + u;
                b2[h * 65536 + row] =
                    rs * (dot[h] - mu * As[1536 + h]) + As[1544 + h];
            }
        }
    }
    grid_sync(lsense);

    // ---------------- stage 2: attention ----------------
    {
        float* k_sh = (float*)smem;                 // 256*32 floats = 32 KiB
        float* v_sh = (float*)(smem + 32768);       // 32 KiB
        int h = b & 7, s = (b >> 3) & 7, it = b >> 6;
        const float* kb = k_t + (size_t)(h * M_ROWS + s * N_RES) * D_DIM;
        const float* vb = v_t + (size_t)(h * M_ROWS + s * N_RES) * D_DIM;
        for (int idx = t; idx < 2048; idx += 256) {
            ((float4*)k_sh)[idx] = ((const float4*)kb)[idx];
            ((float4*)v_sh)[idx] = ((const float4*)vb)[idx];
        }
        __syncthreads();
        int jp = t & 3, dg = (t >> 2) & 7, li = t >> 5;
        int d0 = dg * 4;
        const float SCL2 = 0.17677669529663687f * LOG2E;
        int ig[4], mrow[4];
        float qs[4][4];
#pragma unroll
        for (int r = 0; r < 4; r++) {
            ig[r] = it * 32 + r * 8 + li;
            mrow[r] = s * N_RES + ig[r];
            float4 q4 =
                *(const float4*)&q_t[(size_t)(h * M_ROWS + mrow[r]) * D_DIM + d0];
            qs[r][0] = q4.x * SCL2; qs[r][1] = q4.y * SCL2;
            qs[r][2] = q4.z * SCL2; qs[r][3] = q4.w * SCL2;
        }
        float den[4][4] = {}, acc[4][4] = {};
        const float* bbase = b2 + h * 65536;
        for (int js4 = 0; js4 < 16; js4++) {
            float bbv[4][4];
#pragma unroll
            for (int r = 0; r < 4; r++)
                *(float4*)&bbv[r][0] =
                    *(const float4*)&bbase[ig[r] * 256 + jp * 64 + js4 * 4];
#pragma unroll
            for (int u = 0; u < 4; u++) {
                int j = jp * 64 + js4 * 4 + u;
                float ka[4], va[4];
                *(float4*)ka = *(const float4*)&k_sh[j * 32 + d0];
                *(float4*)va = *(const float4*)&v_sh[j * 32 + d0];
#pragma unroll
                for (int r = 0; r < 4; r++) {
#pragma unroll
                    for (int c = 0; c < 4; c++) {
                        float e = __builtin_amdgcn_exp2f(qs[r][c] * ka[c] + bbv[r][u]);
                        den[r][c] += e;
                        acc[r][c] += e * va[c];
                    }
                }
            }
        }
#pragma unroll
        for (int r = 0; r < 4; r++)
#pragma unroll
            for (int c = 0; c < 4; c++) {
                den[r][c] = quad_sum(den[r][c]);
                acc[r][c] = quad_sum(acc[r][c]);
            }
        if (jp == 0) {
#pragma unroll
            for (int r = 0; r < 4; r++) {
                float4 g4 =
                    *(const float4*)&g_t[(size_t)(h * M_ROWS + mrow[r]) * D_DIM + d0];
                float o[4];
                o[0] = g4.x * acc[r][0] / den[r][0];
                o[1] = g4.y * acc[r][1] / den[r][1];
                o[2] = g4.z * acc[r][2] / den[r][2];
                o[3] = g4.w * acc[r][3] / den[r][3];
                unsigned short hi[4], lo[4];
#pragma unroll
                for (int c = 0; c < 4; c++) {
                    hi[c] = bf16rn(o[c]);
                    lo[c] = bf16rn(o[c] - __uint_as_float((unsigned)hi[c] << 16));
                }
                size_t base = (size_t)mrow[r] * 256 + h * 32 + d0;
                uint2 ph, pl;
                ph.x = (unsigned)hi[0] | ((unsigned)hi[1] << 16);
                ph.y = (unsigned)hi[2] | ((unsigned)hi[3] << 16);
                pl.x = (unsigned)lo[0] | ((unsigned)lo[1] << 16);
                pl.y = (unsigned)lo[2] | ((unsigned)lo[3] << 16);
                *(uint2*)&ao_hi[base] = ph;
                *(uint2*)&ao_lo[base] = pl;
            }
        }
    }
    grid_sync(lsense);

    // ---------------- stage 3: out projection, 16x64 tile/block ------------
    {
        unsigned short* As = (unsigned short*)smem;            // 16*72*2=2304
        unsigned short* Bs = (unsigned short*)(smem + 2304);   // 64*72*2=9216
        float* Cs = (float*)(smem + 2304 + 9216);              // 16*68*4=4352
        int n0 = (b & 3) * 64, m0 = (b >> 2) * 16;
        int w = t >> 6, L = t & 63;
        int wn = w * 16;
        int l15 = L & 15, l4 = L >> 4;
        int alm = t >> 3, alk = (t & 7) * 8;   // As staging: t<128
        bool doA = (t < 128);
        floatx4 acc = (floatx4){0, 0, 0, 0};
        short8 pa;
        if (doA) pa = *(const short8*)&ao_hi[(m0 + alm) * 256 + alk];
        short8 pb[2];
#pragma unroll
        for (int j = 0; j < 2; j++) {
            int id = t + 256 * j;
            int bn = id >> 3, bc = (id & 7) * 8;
            pb[j] = *(const short8*)&wouthiT[(n0 + bn) * 256 + bc];
        }
        for (int r = 0; r < 12; r++) {
            __syncthreads();
            if (doA) *(short8*)&As[alm * 72 + alk] = pa;
#pragma unroll
            for (int j = 0; j < 2; j++) {
                int id = t + 256 * j;
                int bn = id >> 3, bc = (id & 7) * 8;
                *(short8*)&Bs[bn * 72 + bc] = pb[j];
            }
            __syncthreads();
            if (r < 11) {
                int rn = r + 1;
                int seg = rn >> 2, kb = (rn & 3) * 64;
                const unsigned short* An = (seg == 1) ? ao_lo : ao_hi;
                const unsigned short* Bn = (seg == 2) ? woutloT : wouthiT;
                if (doA) pa = *(const short8*)&An[(m0 + alm) * 256 + kb + alk];
#pragma unroll
                for (int j = 0; j < 2; j++) {
                    int id = t + 256 * j;
                    int bn = id >> 3, bc = (id & 7) * 8;
                    pb[j] = *(const short8*)&Bn[(n0 + bn) * 256 + kb + bc];
                }
            }
#pragma unroll
            for (int ks = 0; ks < 2; ks++) {
                int ko = ks * 32 + l4 * 8;
                short8 af = *(short8*)&As[l15 * 72 + ko];
                short8 bf = *(short8*)&Bs[(wn + l15) * 72 + ko];
                acc = __builtin_amdgcn_mfma_f32_16x16x32_bf16(af, bf, acc, 0, 0, 0);
            }
        }
#pragma unroll
        for (int rg = 0; rg < 4; rg++)
            Cs[(l4 * 4 + rg) * 68 + wn + l15] = acc[rg];
        __syncthreads();
        {
            int m = t >> 4, nc = (t & 15) * 4;
            float4 v = *(float4*)&Cs[m * 68 + nc];
            float4 bb = *(const float4*)&b_out[n0 + nc];
            float4 o;
            o.x = v.x + bb.x; o.y = v.y + bb.y;
            o.z = v.z + bb.z; o.w = v.w + bb.w;
            *(float4*)&out[(size_t)(m0 + m) * 256 + n0 + nc] = o;
        }
    }
}

extern "C" void kernel_launch(void* const* d_in, const int* in_sizes, int n_in,
                              void* d_out, int out_size, void* d_ws, size_t ws_size,
                              hipStream_t stream)
{
    const float* msa_rep   = (const float*)d_in[0];
    const float* pair_rep  = (const float*)d_in[1];
    const float* ln_w      = (const float*)d_in[2];
    const float* ln_b      = (const float*)d_in[3];
    const float* w_qkv     = (const float*)d_in[4];
    const float* ln_pair_w = (const float*)d_in[5];
    const float* ln_pair_b = (const float*)d_in[6];
    const float* w_b       = (const float*)d_in[7];
    const float* w_g       = (const float*)d_in[8];
    const float* w_out     = (const float*)d_in[9];
    const float* b_out     = (const float*)d_in[10];
    float* out = (float*)d_out;

    float* ws = (float*)d_ws;
    const size_t CH = 524288;     // 2048*256 floats
    float* q_t = ws + 0 * CH;
    float* k_t = ws + 1 * CH;
    float* v_t = ws + 2 * CH;
    float* g_t = ws + 3 * CH;
    float* b2  = ws + 4 * CH;
    unsigned short* ao_hi   = (unsigned short*)(ws + 5 * CH);
    unsigned short* ao_lo   = ao_hi + (size_t)M_ROWS * 256;
    unsigned short* xhi     = (unsigned short*)(ws + 6 * CH);
    unsigned short* xlo     = xhi + (size_t)M_ROWS * 256;
    unsigned short* whiT    = (unsigned short*)(ws + 7 * CH);
    unsigned short* wloT    = whiT + (size_t)XW_N * 256;
    unsigned short* wouthiT = (unsigned short*)(ws + 8 * CH);
    unsigned short* woutloT = wouthiT + 65536;

    fused_kernel<<<GRID_BLKS, 256, 0, stream>>>(
        msa_rep, ln_w, ln_b, w_qkv, w_g, w_out,
        pair_rep, ln_pair_w, ln_pair_b, w_b,
        b_out, out,
        q_t, k_t, v_t, g_t, b2,
        xhi, xlo, whiT, wloT, wouthiT, woutloT, ao_hi, ao_lo);
}

// Round 3
// 149.225 us; speedup vs baseline: 2.0510x; 2.0510x over previous
//
#include <hip/hip_runtime.h>
#include <math.h>

#define S_DIM 8
#define N_RES 256
#define MSA_DIM 256
#define PAIR_DIM 128
#define D_DIM 32
#define H_DIM 8
#define M_ROWS (S_DIM * N_RES)      // 2048
#define QKV_N (3 * H_DIM * D_DIM)   // 768
#define HD (H_DIM * D_DIM)          // 256
#define XW_N 1024                   // qkv(768) + gate(256)
#define LOG2E 1.4426950408889634f

typedef __attribute__((ext_vector_type(8))) short short8;
typedef __attribute__((ext_vector_type(4))) float floatx4;

// ---- wave64 sum via DPP; total lands in lane 63
#define DPP_ADD(x, ctrl, rmask)                                                \
    x += __int_as_float(__builtin_amdgcn_update_dpp(                           \
        0, __float_as_int(x), (ctrl), (rmask), 0xf, true))

__device__ __forceinline__ float wave_sum63(float x) {
    DPP_ADD(x, 0x111, 0xf);
    DPP_ADD(x, 0x112, 0xf);
    DPP_ADD(x, 0x114, 0xf);
    DPP_ADD(x, 0x118, 0xf);
    DPP_ADD(x, 0x142, 0xa);
    DPP_ADD(x, 0x143, 0xc);
    return x;
}

__device__ __forceinline__ float quad_sum(float x) {
    x += __int_as_float(__builtin_amdgcn_update_dpp(
        0, __float_as_int(x), 0xB1, 0xf, 0xf, true));
    x += __int_as_float(__builtin_amdgcn_update_dpp(
        0, __float_as_int(x), 0x4E, 0xf, 0xf, true));
    return x;
}

__device__ __forceinline__ unsigned short bf16rn(float v) {
    unsigned u = __float_as_uint(v);
    return (unsigned short)((u + 0x7FFF + ((u >> 16) & 1)) >> 16);
}

// =========== Kernel 1 "prep": LN(msa) + wconv, 512 compact blocks ==========
// per block: LN of 4 msa rows (one wave each) ; t<64: wconv W units ;
// t in [64,80): wconv w_out units.
__global__ __launch_bounds__(256) void prep_kernel(
    const float* __restrict__ w_qkv, const float* __restrict__ w_g,
    unsigned short* __restrict__ whiT, unsigned short* __restrict__ wloT,
    const float* __restrict__ w_out,
    unsigned short* __restrict__ wouthiT, unsigned short* __restrict__ woutloT,
    const float* __restrict__ msa, const float* __restrict__ lnw,
    const float* __restrict__ lnb, unsigned short* __restrict__ xhi,
    unsigned short* __restrict__ xlo)
{
    int b = blockIdx.x;
    int t = threadIdx.x;

    // ---- LayerNorm: one wave per row, 4 rows/block (rows = b*4+wave) ----
    {
        int wv = t >> 6, l = t & 63;
        int row = b * 4 + wv;
        float4 v4 = *(const float4*)&msa[(size_t)row * 256 + l * 4];
        float s1 = v4.x + v4.y + v4.z + v4.w;
        float s2 = v4.x * v4.x + v4.y * v4.y + v4.z * v4.z + v4.w * v4.w;
        s1 = wave_sum63(s1);
        s2 = wave_sum63(s2);
        float S1 = __int_as_float(__builtin_amdgcn_readlane(__float_as_int(s1), 63));
        float S2 = __int_as_float(__builtin_amdgcn_readlane(__float_as_int(s2), 63));
        float mu = S1 * (1.0f / 256.0f);
        float var = S2 * (1.0f / 256.0f) - mu * mu;
        float rs = rsqrtf(var + 1e-5f);
        float4 w4 = *(const float4*)&lnw[l * 4];
        float4 bb4 = *(const float4*)&lnb[l * 4];
        float y[4];
        y[0] = (v4.x - mu) * rs * w4.x + bb4.x;
        y[1] = (v4.y - mu) * rs * w4.y + bb4.y;
        y[2] = (v4.z - mu) * rs * w4.z + bb4.z;
        y[3] = (v4.w - mu) * rs * w4.w + bb4.w;
        unsigned short hh[4], ll[4];
#pragma unroll
        for (int i = 0; i < 4; i++) {
            hh[i] = bf16rn(y[i]);
            ll[i] = bf16rn(y[i] - __uint_as_float((unsigned)hh[i] << 16));
        }
        uint2 ph, pl;
        ph.x = (unsigned)hh[0] | ((unsigned)hh[1] << 16);
        ph.y = (unsigned)hh[2] | ((unsigned)hh[3] << 16);
        pl.x = (unsigned)ll[0] | ((unsigned)ll[1] << 16);
        pl.y = (unsigned)ll[2] | ((unsigned)ll[3] << 16);
        *(uint2*)&xhi[(size_t)row * 256 + l * 4] = ph;
        *(uint2*)&xlo[(size_t)row * 256 + l * 4] = pl;
    }

    // ---- wconv W = [w_qkv | w_g]: 32768 units = 512 blocks * 64 ----
    if (t < 64) {
        int id = b * 64 + t;
        int n = id >> 5, oct = id & 31, k0 = oct * 8;
        const float* src;
        int stride;
        if (n < QKV_N) { src = w_qkv + n; stride = QKV_N; }
        else           { src = w_g + (n - QKV_N); stride = HD; }
        unsigned short h8[8], l8[8];
#pragma unroll
        for (int j = 0; j < 8; j++) {
            float v = src[(size_t)(k0 + j) * stride];
            unsigned short h = bf16rn(v);
            h8[j] = h;
            l8[j] = bf16rn(v - __uint_as_float((unsigned)h << 16));
        }
        *(short8*)&whiT[n * 256 + k0] = *(short8*)h8;
        *(short8*)&wloT[n * 256 + k0] = *(short8*)l8;
    } else if (t < 80) {
        // wconv w_out (ao-layout row perm): 8192 units = 512 * 16
        int id = b * 16 + (t - 64);
        int n = id >> 5, oct = id & 31, k0 = oct * 8;
        unsigned short h8[8], l8[8];
#pragma unroll
        for (int j = 0; j < 8; j++) {
            int k = k0 + j;
            int wrow = (k & 31) * 8 + (k >> 5);
            float v = w_out[(size_t)wrow * 256 + n];
            unsigned short h = bf16rn(v);
            h8[j] = h;
            l8[j] = bf16rn(v - __uint_as_float((unsigned)h << 16));
        }
        *(short8*)&wouthiT[n * 256 + k0] = *(short8*)h8;
        *(short8*)&woutloT[n * 256 + k0] = *(short8*)l8;
    }
}

// ====== Kernel 2 "mid": pair_bias (1024 blocks) || xw GEMM (512 blocks) ====
// Roles interleaved (bx%3==2 -> GEMM) so HBM-streaming pair blocks and
// latency-bound MFMA blocks co-reside on each CU.
__global__ __launch_bounds__(256) void mid_kernel(
    const float* __restrict__ pair, const float* __restrict__ lw,
    const float* __restrict__ lb, const float* __restrict__ wb,
    float* __restrict__ b2,
    const unsigned short* __restrict__ xhi, const unsigned short* __restrict__ xlo,
    const unsigned short* __restrict__ whiT, const unsigned short* __restrict__ wloT,
    float* __restrict__ q_t, float* __restrict__ k_t,
    float* __restrict__ v_t, float* __restrict__ g_t)
{
    __shared__ __align__(16) char smem[35840];  // GEMM: As|Bs|Cs ; pair: 8320B
    int bx = blockIdx.x;
    int t = threadIdx.x;
    int g3 = bx / 3, r3 = bx - g3 * 3;

    if (r3 != 2) {
        // ---------------- pair_bias ----------------
        float* As = (float*)smem;
        float* Spart = (float*)smem + 1552;
        float* Qpart = (float*)smem + 1816;
        int pair_id = g3 * 2 + r3;            // [0,1024)
        if (t < 128) {
            float lwc = lw[t];
#pragma unroll
            for (int h = 0; h < 8; h++)
                As[t * 12 + h] = lwc * wb[t * 8 + h] * LOG2E;
        }
        __syncthreads();
        {
            int h = t >> 5, seg = t & 31, cbase = seg * 4;
            float sa = 0, sq = 0;
#pragma unroll
            for (int cc = 0; cc < 4; cc++) {
                int c = cbase + cc;
                sa += As[c * 12 + h];
                sq += lb[c] * wb[c * 8 + h];
            }
            Spart[h * 33 + seg] = sa;
            Qpart[h * 33 + seg] = sq * LOG2E;
        }
        __syncthreads();
        if (t < 8) {
            float s = 0, q = 0;
#pragma unroll
            for (int j = 0; j < 32; j++) {
                s += Spart[t * 33 + j];
                q += Qpart[t * 33 + j];
            }
            As[1536 + t] = s;
            As[1544 + t] = q;
        }
        __syncthreads();
        int row = pair_id * 64 + (t >> 2);
        int q = t & 3;
        const float* in = pair + (size_t)row * PAIR_DIM;
        float4 x4[8];
#pragma unroll
        for (int it = 0; it < 8; it++)
            x4[it] = *(const float4*)&in[it * 16 + q * 4];
        float s = 0, s2 = 0;
        float dot[8] = {};
#pragma unroll
        for (int it = 0; it < 8; it++) {
            float xk[4];
            *(float4*)xk = x4[it];
#pragma unroll
            for (int k = 0; k < 4; k++) {
                int c = it * 16 + q * 4 + k;
                float xv = xk[k];
                s += xv; s2 += xv * xv;
                float4 A0 = *(const float4*)&As[c * 12];
                float4 A1 = *(const float4*)&As[c * 12 + 4];
                dot[0] += xv * A0.x; dot[1] += xv * A0.y;
                dot[2] += xv * A0.z; dot[3] += xv * A0.w;
                dot[4] += xv * A1.x; dot[5] += xv * A1.y;
                dot[6] += xv * A1.z; dot[7] += xv * A1.w;
            }
        }
        s = quad_sum(s);
        s2 = quad_sum(s2);
#pragma unroll
        for (int h = 0; h < 8; h++) dot[h] = quad_sum(dot[h]);
        float mu = s * (1.0f / 128.0f);
        float var = s2 * (1.0f / 128.0f) - mu * mu;
        float rs = rsqrtf(var + 1e-5f);
        int h0 = q * 2;
#pragma unroll
        for (int u = 0; u < 2; u++) {
            int h = h0 + u;
            b2[h * 65536 + row] = rs * (dot[h] - mu * As[1536 + h]) + As[1544 + h];
        }
    } else {
        // ---------------- xw GEMM, 64x64 tile ----------------
        unsigned short* As = (unsigned short*)smem;          // 64*72
        unsigned short* Bs = As + 64 * 72;                   // 64*72
        float* Cs = (float*)(smem + 18432);                  // 64*68
        int gid = g3;                                        // [0,512)
        int n0 = (gid & 15) * 64, m0 = (gid >> 4) * 64;
        int w = t >> 6, L = t & 63;
        int wm = (w & 1) * 32, wn = (w >> 1) * 32;
        int l15 = L & 15, l4 = L >> 4;
        int alm = t >> 3, alk = (t & 7) * 8;
        floatx4 acc[2][2];
#pragma unroll
        for (int a = 0; a < 2; a++)
#pragma unroll
            for (int c = 0; c < 2; c++) acc[a][c] = (floatx4){0, 0, 0, 0};

        short8 pa0 = *(const short8*)&xhi[(m0 + alm) * 256 + alk];
        short8 pa1 = *(const short8*)&xhi[(m0 + alm + 32) * 256 + alk];
        short8 pb[2];
#pragma unroll
        for (int j = 0; j < 2; j++) {
            int id = t + 256 * j;
            int bn = id >> 3, bc = (id & 7) * 8;
            pb[j] = *(const short8*)&whiT[(n0 + bn) * 256 + bc];
        }

        for (int r = 0; r < 12; r++) {
            __syncthreads();
            *(short8*)&As[alm * 72 + alk] = pa0;
            *(short8*)&As[(alm + 32) * 72 + alk] = pa1;
#pragma unroll
            for (int j = 0; j < 2; j++) {
                int id = t + 256 * j;
                int bn = id >> 3, bc = (id & 7) * 8;
                *(short8*)&Bs[bn * 72 + bc] = pb[j];
            }
            __syncthreads();
            if (r < 11) {
                int rn = r + 1;
                int seg = rn >> 2, kb = (rn & 3) * 64;
                const unsigned short* An = (seg == 1) ? xlo : xhi;
                const unsigned short* Bn = (seg == 2) ? wloT : whiT;
                pa0 = *(const short8*)&An[(m0 + alm) * 256 + kb + alk];
                pa1 = *(const short8*)&An[(m0 + alm + 32) * 256 + kb + alk];
#pragma unroll
                for (int j = 0; j < 2; j++) {
                    int id = t + 256 * j;
                    int bn = id >> 3, bc = (id & 7) * 8;
                    pb[j] = *(const short8*)&Bn[(n0 + bn) * 256 + kb + bc];
                }
            }
#pragma unroll
            for (int ks = 0; ks < 2; ks++) {
                int ko = ks * 32 + l4 * 8;
                short8 af[2], bf[2];
#pragma unroll
                for (int a = 0; a < 2; a++)
                    af[a] = *(short8*)&As[(wm + a * 16 + l15) * 72 + ko];
#pragma unroll
                for (int c = 0; c < 2; c++)
                    bf[c] = *(short8*)&Bs[(wn + c * 16 + l15) * 72 + ko];
#pragma unroll
                for (int a = 0; a < 2; a++)
#pragma unroll
                    for (int c = 0; c < 2; c++)
                        acc[a][c] = __builtin_amdgcn_mfma_f32_16x16x32_bf16(
                            af[a], bf[c], acc[a][c], 0, 0, 0);
            }
        }
#pragma unroll
        for (int a = 0; a < 2; a++)
#pragma unroll
            for (int c = 0; c < 2; c++) {
                int nl = wn + c * 16 + l15;
#pragma unroll
                for (int rg = 0; rg < 4; rg++) {
                    int ml = wm + a * 16 + l4 * 4 + rg;
                    Cs[ml * 68 + nl] = acc[a][c][rg];
                }
            }
        __syncthreads();
        int qkv_mode = (n0 < QKV_N);
        int chunk = n0 >> 8;
        int dbase = (n0 & 255) >> 3;
#pragma unroll
        for (int j = 0; j < 4; j++) {
            int id = t + 256 * j;             // [0,1024)
            int m = id >> 4;
            int h = (id >> 1) & 7;
            int dq = id & 1;
            float vals[4];
#pragma unroll
            for (int jj = 0; jj < 4; jj++)
                vals[jj] = Cs[m * 68 + (dq * 4 + jj) * 8 + h];
            int mm = m0 + m;
            int daddr = dbase + dq * 4;
            if (qkv_mode) {
                float* dst = (chunk == 0) ? q_t : ((chunk == 1) ? k_t : v_t);
                *(float4*)&dst[(size_t)(h * M_ROWS + mm) * D_DIM + daddr] =
                    *(float4*)vals;
            } else {
                float4 o;
                o.x = 1.0f / (1.0f + __expf(-vals[0]));
                o.y = 1.0f / (1.0f + __expf(-vals[1]));
                o.z = 1.0f / (1.0f + __expf(-vals[2]));
                o.w = 1.0f / (1.0f + __expf(-vals[3]));
                *(float4*)&g_t[(size_t)(h * M_ROWS + mm) * D_DIM + daddr] = o;
            }
        }
    }
}

// ---------------- Kernel 3: attention; emits ao as bf16 hi/lo --------------
// Block map: h = bx&7 (XCD-locality: all blocks of head h share an XCD via
// round-robin dispatch, so b2's 2MB head-slice stays L2-resident across the
// 8x s-reuse), s = (bx>>3)&7, it = bx>>6.
// LDS stride 32 floats (64 KiB total -> 2 blocks/CU). Conflict-free: the 4
// j-rows a wave touches differ by 64 rows (j*32 dwords -> bank contribution
// 0 mod 32), and dg spans all 8 bank groups, so each b128 phase covers all
// 32 banks; lanes 32-63 broadcast the same addresses as 0-31.
__global__ __launch_bounds__(256) void attn_kernel(
    const float* __restrict__ q_t, const float* __restrict__ k_t,
    const float* __restrict__ v_t, const float* __restrict__ g_t,
    const float* __restrict__ b2, unsigned short* __restrict__ ao_hi,
    unsigned short* __restrict__ ao_lo)
{
    __shared__ float k_sh[256][32];
    __shared__ float v_sh[256][32];
    int blk = blockIdx.x;
    int h = blk & 7, s = (blk >> 3) & 7, it = blk >> 6;
    int t = threadIdx.x;
    const float* kb = k_t + (size_t)(h * M_ROWS + s * N_RES) * D_DIM;
    const float* vb = v_t + (size_t)(h * M_ROWS + s * N_RES) * D_DIM;
    for (int idx = t; idx < 2048; idx += 256) {
        ((float4*)k_sh)[idx] = ((const float4*)kb)[idx];
        ((float4*)v_sh)[idx] = ((const float4*)vb)[idx];
    }
    __syncthreads();
    int jp = t & 3, dg = (t >> 2) & 7, li = t >> 5;
    int d0 = dg * 4;
    const float SCL2 = 0.17677669529663687f * LOG2E;
    int ig[4], mrow[4];
    float qs[4][4];
#pragma unroll
    for (int r = 0; r < 4; r++) {
        ig[r] = it * 32 + r * 8 + li;
        mrow[r] = s * N_RES + ig[r];
        float4 q4 = *(const float4*)&q_t[(size_t)(h * M_ROWS + mrow[r]) * D_DIM + d0];
        qs[r][0] = q4.x * SCL2; qs[r][1] = q4.y * SCL2;
        qs[r][2] = q4.z * SCL2; qs[r][3] = q4.w * SCL2;
    }
    float den[4][4] = {}, acc[4][4] = {};
    const float* bbase = b2 + h * 65536;
    for (int js4 = 0; js4 < 16; js4++) {
        float bb[4][4];
#pragma unroll
        for (int r = 0; r < 4; r++)
            *(float4*)&bb[r][0] =
                *(const float4*)&bbase[ig[r] * 256 + jp * 64 + js4 * 4];
#pragma unroll
        for (int u = 0; u < 4; u++) {
            int j = jp * 64 + js4 * 4 + u;
            float ka[4], va[4];
            *(float4*)ka = *(const float4*)&k_sh[j][d0];
            *(float4*)va = *(const float4*)&v_sh[j][d0];
#pragma unroll
            for (int r = 0; r < 4; r++) {
#pragma unroll
                for (int c = 0; c < 4; c++) {
                    float e = __builtin_amdgcn_exp2f(qs[r][c] * ka[c] + bb[r][u]);
                    den[r][c] += e;
                    acc[r][c] += e * va[c];
                }
            }
        }
    }
#pragma unroll
    for (int r = 0; r < 4; r++)
#pragma unroll
        for (int c = 0; c < 4; c++) {
            den[r][c] = quad_sum(den[r][c]);
            acc[r][c] = quad_sum(acc[r][c]);
        }
    if (jp == 0) {
#pragma unroll
        for (int r = 0; r < 4; r++) {
            float4 g4 = *(const float4*)&g_t[(size_t)(h * M_ROWS + mrow[r]) * D_DIM + d0];
            float o[4];
            o[0] = g4.x * acc[r][0] * __builtin_amdgcn_rcpf(den[r][0]);
            o[1] = g4.y * acc[r][1] * __builtin_amdgcn_rcpf(den[r][1]);
            o[2] = g4.z * acc[r][2] * __builtin_amdgcn_rcpf(den[r][2]);
            o[3] = g4.w * acc[r][3] * __builtin_amdgcn_rcpf(den[r][3]);
            unsigned short hi[4], lo[4];
#pragma unroll
            for (int c = 0; c < 4; c++) {
                hi[c] = bf16rn(o[c]);
                lo[c] = bf16rn(o[c] - __uint_as_float((unsigned)hi[c] << 16));
            }
            size_t base = (size_t)mrow[r] * 256 + h * 32 + d0;
            uint2 ph, pl;
            ph.x = (unsigned)hi[0] | ((unsigned)hi[1] << 16);
            ph.y = (unsigned)hi[2] | ((unsigned)hi[3] << 16);
            pl.x = (unsigned)lo[0] | ((unsigned)lo[1] << 16);
            pl.y = (unsigned)lo[2] | ((unsigned)lo[3] << 16);
            *(uint2*)&ao_hi[base] = ph;
            *(uint2*)&ao_lo[base] = pl;
        }
    }
}

// ------- Kernel 4: out projection via bf16x3 MFMA + bias -------------------
// 32x64 tiles -> grid (4,64) = 256 blocks.
__global__ __launch_bounds__(256) void out_mfma_kernel(
    const unsigned short* __restrict__ ahi, const unsigned short* __restrict__ alo,
    const unsigned short* __restrict__ whi, const unsigned short* __restrict__ wlo,
    const float* __restrict__ bias, float* __restrict__ out)
{
    __shared__ unsigned short As[32 * 72];
    __shared__ unsigned short Bs[64 * 72];
    __shared__ float Cs[32 * 68];
    int t = threadIdx.x;
    int n0 = blockIdx.x * 64, m0 = blockIdx.y * 32;
    int w = t >> 6, L = t & 63;
    int wm = (w & 1) * 16, wn = (w >> 1) * 32;
    int l15 = L & 15, l4 = L >> 4;
    int alm = t >> 3, alk = (t & 7) * 8;
    floatx4 acc[2];
#pragma unroll
    for (int b = 0; b < 2; b++) acc[b] = (floatx4){0, 0, 0, 0};

    short8 pa0 = *(const short8*)&ahi[(m0 + alm) * 256 + alk];
    short8 pb[2];
#pragma unroll
    for (int j = 0; j < 2; j++) {
        int id = t + 256 * j;
        int bn = id >> 3, bc = (id & 7) * 8;
        pb[j] = *(const short8*)&whi[(n0 + bn) * 256 + bc];
    }

    for (int r = 0; r < 12; r++) {
        __syncthreads();
        *(short8*)&As[alm * 72 + alk] = pa0;
#pragma unroll
        for (int j = 0; j < 2; j++) {
            int id = t + 256 * j;
            int bn = id >> 3, bc = (id & 7) * 8;
            *(short8*)&Bs[bn * 72 + bc] = pb[j];
        }
        __syncthreads();
        if (r < 11) {
            int rn = r + 1;
            int seg = rn >> 2, kb = (rn & 3) * 64;
            const unsigned short* An = (seg == 1) ? alo : ahi;
            const unsigned short* Bn = (seg == 2) ? wlo : whi;
            pa0 = *(const short8*)&An[(m0 + alm) * 256 + kb + alk];
#pragma unroll
            for (int j = 0; j < 2; j++) {
                int id = t + 256 * j;
                int bn = id >> 3, bc = (id & 7) * 8;
                pb[j] = *(const short8*)&Bn[(n0 + bn) * 256 + kb + bc];
            }
        }
#pragma unroll
        for (int ks = 0; ks < 2; ks++) {
            int ko = ks * 32 + l4 * 8;
            short8 af, bf[2];
            af = *(short8*)&As[(wm + l15) * 72 + ko];
#pragma unroll
            for (int b = 0; b < 2; b++)
                bf[b] = *(short8*)&Bs[(wn + b * 16 + l15) * 72 + ko];
#pragma unroll
            for (int b = 0; b < 2; b++)
                acc[b] = __builtin_amdgcn_mfma_f32_16x16x32_bf16(
                    af, bf[b], acc[b], 0, 0, 0);
        }
    }
#pragma unroll
    for (int b = 0; b < 2; b++) {
        int nl = wn + b * 16 + l15;
#pragma unroll
        for (int rg = 0; rg < 4; rg++) {
            int ml = wm + l4 * 4 + rg;
            Cs[ml * 68 + nl] = acc[b][rg];
        }
    }
    __syncthreads();
#pragma unroll
    for (int j = 0; j < 2; j++) {
        int id = t + 256 * j;                 // [0,512)
        int m = id >> 4, nc = (id & 15) * 4;
        float4 v = *(float4*)&Cs[m * 68 + nc];
        float4 bb = *(const float4*)&bias[n0 + nc];
        float4 o;
        o.x = v.x + bb.x; o.y = v.y + bb.y;
        o.z = v.z + bb.z; o.w = v.w + bb.w;
        *(float4*)&out[(size_t)(m0 + m) * 256 + n0 + nc] = o;
    }
}

extern "C" void kernel_launch(void* const* d_in, const int* in_sizes, int n_in,
                              void* d_out, int out_size, void* d_ws, size_t ws_size,
                              hipStream_t stream)
{
    const float* msa_rep   = (const float*)d_in[0];
    const float* pair_rep  = (const float*)d_in[1];
    const float* ln_w      = (const float*)d_in[2];
    const float* ln_b      = (const float*)d_in[3];
    const float* w_qkv     = (const float*)d_in[4];
    const float* ln_pair_w = (const float*)d_in[5];
    const float* ln_pair_b = (const float*)d_in[6];
    const float* w_b       = (const float*)d_in[7];
    const float* w_g       = (const float*)d_in[8];
    const float* w_out     = (const float*)d_in[9];
    const float* b_out     = (const float*)d_in[10];
    float* out = (float*)d_out;

    float* ws = (float*)d_ws;
    const size_t CH = 524288;     // 2048*256 floats
    float* q_t = ws + 0 * CH;
    float* k_t = ws + 1 * CH;
    float* v_t = ws + 2 * CH;
    float* g_t = ws + 3 * CH;
    float* b2  = ws + 4 * CH;
    unsigned short* ao_hi   = (unsigned short*)(ws + 5 * CH);
    unsigned short* ao_lo   = ao_hi + (size_t)M_ROWS * 256;
    unsigned short* xhi     = (unsigned short*)(ws + 6 * CH);
    unsigned short* xlo     = xhi + (size_t)M_ROWS * 256;
    unsigned short* whiT    = (unsigned short*)(ws + 7 * CH);
    unsigned short* wloT    = whiT + (size_t)XW_N * 256;
    unsigned short* wouthiT = (unsigned short*)(ws + 8 * CH);
    unsigned short* woutloT = wouthiT + 65536;

    prep_kernel<<<512, 256, 0, stream>>>(
        w_qkv, w_g, whiT, wloT,
        w_out, wouthiT, woutloT,
        msa_rep, ln_w, ln_b, xhi, xlo);

    mid_kernel<<<1536, 256, 0, stream>>>(
        pair_rep, ln_pair_w, ln_pair_b, w_b, b2,
        xhi, xlo, whiT, wloT, q_t, k_t, v_t, g_t);

    attn_kernel<<<512, 256, 0, stream>>>(q_t, k_t, v_t, g_t, b2, ao_hi, ao_lo);

    out_mfma_kernel<<<dim3(4, 64), 256, 0, stream>>>(
        ao_hi, ao_lo, wouthiT, woutloT, b_out, out);
}

// Round 4
// 143.891 us; speedup vs baseline: 2.1270x; 1.0371x over previous
//
#include <hip/hip_runtime.h>
#include <math.h>

#define S_DIM 8
#define N_RES 256
#define MSA_DIM 256
#define PAIR_DIM 128
#define D_DIM 32
#define H_DIM 8
#define M_ROWS (S_DIM * N_RES)      // 2048
#define QKV_N (3 * H_DIM * D_DIM)   // 768
#define HD (H_DIM * D_DIM)          // 256
#define XW_N 1024                   // qkv(768) + gate(256)
#define LOG2E 1.4426950408889634f

typedef __attribute__((ext_vector_type(8))) short short8;
typedef __attribute__((ext_vector_type(4))) float floatx4;

// ---- wave64 sum via DPP; total lands in lane 63
#define DPP_ADD(x, ctrl, rmask)                                                \
    x += __int_as_float(__builtin_amdgcn_update_dpp(                           \
        0, __float_as_int(x), (ctrl), (rmask), 0xf, true))

__device__ __forceinline__ float wave_sum63(float x) {
    DPP_ADD(x, 0x111, 0xf);
    DPP_ADD(x, 0x112, 0xf);
    DPP_ADD(x, 0x114, 0xf);
    DPP_ADD(x, 0x118, 0xf);
    DPP_ADD(x, 0x142, 0xa);
    DPP_ADD(x, 0x143, 0xc);
    return x;
}

__device__ __forceinline__ float quad_sum(float x) {
    x += __int_as_float(__builtin_amdgcn_update_dpp(
        0, __float_as_int(x), 0xB1, 0xf, 0xf, true));
    x += __int_as_float(__builtin_amdgcn_update_dpp(
        0, __float_as_int(x), 0x4E, 0xf, 0xf, true));
    return x;
}

__device__ __forceinline__ unsigned short bf16rn(float v) {
    unsigned u = __float_as_uint(v);
    return (unsigned short)((u + 0x7FFF + ((u >> 16) & 1)) >> 16);
}

// =========== Kernel 1 "prep": LN(msa) + wconv, 512 compact blocks ==========
__global__ __launch_bounds__(256) void prep_kernel(
    const float* __restrict__ w_qkv, const float* __restrict__ w_g,
    unsigned short* __restrict__ whiT, unsigned short* __restrict__ wloT,
    const float* __restrict__ w_out,
    unsigned short* __restrict__ wouthiT, unsigned short* __restrict__ woutloT,
    const float* __restrict__ msa, const float* __restrict__ lnw,
    const float* __restrict__ lnb, unsigned short* __restrict__ xhi,
    unsigned short* __restrict__ xlo)
{
    int b = blockIdx.x;
    int t = threadIdx.x;

    // ---- LayerNorm: one wave per row, 4 rows/block (rows = b*4+wave) ----
    {
        int wv = t >> 6, l = t & 63;
        int row = b * 4 + wv;
        float4 v4 = *(const float4*)&msa[(size_t)row * 256 + l * 4];
        float s1 = v4.x + v4.y + v4.z + v4.w;
        float s2 = v4.x * v4.x + v4.y * v4.y + v4.z * v4.z + v4.w * v4.w;
        s1 = wave_sum63(s1);
        s2 = wave_sum63(s2);
        float S1 = __int_as_float(__builtin_amdgcn_readlane(__float_as_int(s1), 63));
        float S2 = __int_as_float(__builtin_amdgcn_readlane(__float_as_int(s2), 63));
        float mu = S1 * (1.0f / 256.0f);
        float var = S2 * (1.0f / 256.0f) - mu * mu;
        float rs = rsqrtf(var + 1e-5f);
        float4 w4 = *(const float4*)&lnw[l * 4];
        float4 bb4 = *(const float4*)&lnb[l * 4];
        float y[4];
        y[0] = (v4.x - mu) * rs * w4.x + bb4.x;
        y[1] = (v4.y - mu) * rs * w4.y + bb4.y;
        y[2] = (v4.z - mu) * rs * w4.z + bb4.z;
        y[3] = (v4.w - mu) * rs * w4.w + bb4.w;
        unsigned short hh[4], ll[4];
#pragma unroll
        for (int i = 0; i < 4; i++) {
            hh[i] = bf16rn(y[i]);
            ll[i] = bf16rn(y[i] - __uint_as_float((unsigned)hh[i] << 16));
        }
        uint2 ph, pl;
        ph.x = (unsigned)hh[0] | ((unsigned)hh[1] << 16);
        ph.y = (unsigned)hh[2] | ((unsigned)hh[3] << 16);
        pl.x = (unsigned)ll[0] | ((unsigned)ll[1] << 16);
        pl.y = (unsigned)ll[2] | ((unsigned)ll[3] << 16);
        *(uint2*)&xhi[(size_t)row * 256 + l * 4] = ph;
        *(uint2*)&xlo[(size_t)row * 256 + l * 4] = pl;
    }

    // ---- wconv W = [w_qkv | w_g]: 32768 units = 512 blocks * 64 ----
    if (t < 64) {
        int id = b * 64 + t;
        int n = id >> 5, oct = id & 31, k0 = oct * 8;
        const float* src;
        int stride;
        if (n < QKV_N) { src = w_qkv + n; stride = QKV_N; }
        else           { src = w_g + (n - QKV_N); stride = HD; }
        unsigned short h8[8], l8[8];
#pragma unroll
        for (int j = 0; j < 8; j++) {
            float v = src[(size_t)(k0 + j) * stride];
            unsigned short h = bf16rn(v);
            h8[j] = h;
            l8[j] = bf16rn(v - __uint_as_float((unsigned)h << 16));
        }
        *(short8*)&whiT[n * 256 + k0] = *(short8*)h8;
        *(short8*)&wloT[n * 256 + k0] = *(short8*)l8;
    } else if (t < 80) {
        // wconv w_out (ao-layout row perm): 8192 units = 512 * 16
        int id = b * 16 + (t - 64);
        int n = id >> 5, oct = id & 31, k0 = oct * 8;
        unsigned short h8[8], l8[8];
#pragma unroll
        for (int j = 0; j < 8; j++) {
            int k = k0 + j;
            int wrow = (k & 31) * 8 + (k >> 5);
            float v = w_out[(size_t)wrow * 256 + n];
            unsigned short h = bf16rn(v);
            h8[j] = h;
            l8[j] = bf16rn(v - __uint_as_float((unsigned)h << 16));
        }
        *(short8*)&wouthiT[n * 256 + k0] = *(short8*)h8;
        *(short8*)&woutloT[n * 256 + k0] = *(short8*)l8;
    }
}

// ====== Kernel 2 "mid": pair_bias (1024 blocks) || xw GEMM (512 blocks) ====
__global__ __launch_bounds__(256) void mid_kernel(
    const float* __restrict__ pair, const float* __restrict__ lw,
    const float* __restrict__ lb, const float* __restrict__ wb,
    float* __restrict__ b2,
    const unsigned short* __restrict__ xhi, const unsigned short* __restrict__ xlo,
    const unsigned short* __restrict__ whiT, const unsigned short* __restrict__ wloT,
    float* __restrict__ q_t, float* __restrict__ k_t,
    float* __restrict__ v_t, float* __restrict__ g_t)
{
    __shared__ __align__(16) char smem[35840];  // GEMM: As|Bs|Cs ; pair: 8320B
    int bx = blockIdx.x;
    int t = threadIdx.x;
    int g3 = bx / 3, r3 = bx - g3 * 3;

    if (r3 != 2) {
        // ---------------- pair_bias ----------------
        float* As = (float*)smem;
        float* Spart = (float*)smem + 1552;
        float* Qpart = (float*)smem + 1816;
        int pair_id = g3 * 2 + r3;            // [0,1024)
        if (t < 128) {
            float lwc = lw[t];
#pragma unroll
            for (int h = 0; h < 8; h++)
                As[t * 12 + h] = lwc * wb[t * 8 + h] * LOG2E;
        }
        __syncthreads();
        {
            int h = t >> 5, seg = t & 31, cbase = seg * 4;
            float sa = 0, sq = 0;
#pragma unroll
            for (int cc = 0; cc < 4; cc++) {
                int c = cbase + cc;
                sa += As[c * 12 + h];
                sq += lb[c] * wb[c * 8 + h];
            }
            Spart[h * 33 + seg] = sa;
            Qpart[h * 33 + seg] = sq * LOG2E;
        }
        __syncthreads();
        if (t < 8) {
            float s = 0, q = 0;
#pragma unroll
            for (int j = 0; j < 32; j++) {
                s += Spart[t * 33 + j];
                q += Qpart[t * 33 + j];
            }
            As[1536 + t] = s;
            As[1544 + t] = q;
        }
        __syncthreads();
        int row = pair_id * 64 + (t >> 2);
        int q = t & 3;
        const float* in = pair + (size_t)row * PAIR_DIM;
        float4 x4[8];
#pragma unroll
        for (int it = 0; it < 8; it++)
            x4[it] = *(const float4*)&in[it * 16 + q * 4];
        float s = 0, s2 = 0;
        float dot[8] = {};
#pragma unroll
        for (int it = 0; it < 8; it++) {
            float xk[4];
            *(float4*)xk = x4[it];
#pragma unroll
            for (int k = 0; k < 4; k++) {
                int c = it * 16 + q * 4 + k;
                float xv = xk[k];
                s += xv; s2 += xv * xv;
                float4 A0 = *(const float4*)&As[c * 12];
                float4 A1 = *(const float4*)&As[c * 12 + 4];
                dot[0] += xv * A0.x; dot[1] += xv * A0.y;
                dot[2] += xv * A0.z; dot[3] += xv * A0.w;
                dot[4] += xv * A1.x; dot[5] += xv * A1.y;
                dot[6] += xv * A1.z; dot[7] += xv * A1.w;
            }
        }
        s = quad_sum(s);
        s2 = quad_sum(s2);
#pragma unroll
        for (int h = 0; h < 8; h++) dot[h] = quad_sum(dot[h]);
        float mu = s * (1.0f / 128.0f);
        float var = s2 * (1.0f / 128.0f) - mu * mu;
        float rs = rsqrtf(var + 1e-5f);
        int h0 = q * 2;
#pragma unroll
        for (int u = 0; u < 2; u++) {
            int h = h0 + u;
            b2[h * 65536 + row] = rs * (dot[h] - mu * As[1536 + h]) + As[1544 + h];
        }
    } else {
        // ---------------- xw GEMM, 64x64 tile ----------------
        unsigned short* As = (unsigned short*)smem;          // 64*72
        unsigned short* Bs = As + 64 * 72;                   // 64*72
        float* Cs = (float*)(smem + 18432);                  // 64*68
        int gid = g3;                                        // [0,512)
        int n0 = (gid & 15) * 64, m0 = (gid >> 4) * 64;
        int w = t >> 6, L = t & 63;
        int wm = (w & 1) * 32, wn = (w >> 1) * 32;
        int l15 = L & 15, l4 = L >> 4;
        int alm = t >> 3, alk = (t & 7) * 8;
        floatx4 acc[2][2];
#pragma unroll
        for (int a = 0; a < 2; a++)
#pragma unroll
            for (int c = 0; c < 2; c++) acc[a][c] = (floatx4){0, 0, 0, 0};

        short8 pa0 = *(const short8*)&xhi[(m0 + alm) * 256 + alk];
        short8 pa1 = *(const short8*)&xhi[(m0 + alm + 32) * 256 + alk];
        short8 pb[2];
#pragma unroll
        for (int j = 0; j < 2; j++) {
            int id = t + 256 * j;
            int bn = id >> 3, bc = (id & 7) * 8;
            pb[j] = *(const short8*)&whiT[(n0 + bn) * 256 + bc];
        }

        for (int r = 0; r < 12; r++) {
            __syncthreads();
            *(short8*)&As[alm * 72 + alk] = pa0;
            *(short8*)&As[(alm + 32) * 72 + alk] = pa1;
#pragma unroll
            for (int j = 0; j < 2; j++) {
                int id = t + 256 * j;
                int bn = id >> 3, bc = (id & 7) * 8;
                *(short8*)&Bs[bn * 72 + bc] = pb[j];
            }
            __syncthreads();
            if (r < 11) {
                int rn = r + 1;
                int seg = rn >> 2, kb = (rn & 3) * 64;
                const unsigned short* An = (seg == 1) ? xlo : xhi;
                const unsigned short* Bn = (seg == 2) ? wloT : whiT;
                pa0 = *(const short8*)&An[(m0 + alm) * 256 + kb + alk];
                pa1 = *(const short8*)&An[(m0 + alm + 32) * 256 + kb + alk];
#pragma unroll
                for (int j = 0; j < 2; j++) {
                    int id = t + 256 * j;
                    int bn = id >> 3, bc = (id & 7) * 8;
                    pb[j] = *(const short8*)&Bn[(n0 + bn) * 256 + kb + bc];
                }
            }
#pragma unroll
            for (int ks = 0; ks < 2; ks++) {
                int ko = ks * 32 + l4 * 8;
                short8 af[2], bf[2];
#pragma unroll
                for (int a = 0; a < 2; a++)
                    af[a] = *(short8*)&As[(wm + a * 16 + l15) * 72 + ko];
#pragma unroll
                for (int c = 0; c < 2; c++)
                    bf[c] = *(short8*)&Bs[(wn + c * 16 + l15) * 72 + ko];
#pragma unroll
                for (int a = 0; a < 2; a++)
#pragma unroll
                    for (int c = 0; c < 2; c++)
                        acc[a][c] = __builtin_amdgcn_mfma_f32_16x16x32_bf16(
                            af[a], bf[c], acc[a][c], 0, 0, 0);
            }
        }
#pragma unroll
        for (int a = 0; a < 2; a++)
#pragma unroll
            for (int c = 0; c < 2; c++) {
                int nl = wn + c * 16 + l15;
#pragma unroll
                for (int rg = 0; rg < 4; rg++) {
                    int ml = wm + a * 16 + l4 * 4 + rg;
                    Cs[ml * 68 + nl] = acc[a][c][rg];
                }
            }
        __syncthreads();
        int qkv_mode = (n0 < QKV_N);
        int chunk = n0 >> 8;
        int dbase = (n0 & 255) >> 3;
#pragma unroll
        for (int j = 0; j < 4; j++) {
            int id = t + 256 * j;             // [0,1024)
            int m = id >> 4;
            int h = (id >> 1) & 7;
            int dq = id & 1;
            float vals[4];
#pragma unroll
            for (int jj = 0; jj < 4; jj++)
                vals[jj] = Cs[m * 68 + (dq * 4 + jj) * 8 + h];
            int mm = m0 + m;
            int daddr = dbase + dq * 4;
            if (qkv_mode) {
                float* dst = (chunk == 0) ? q_t : ((chunk == 1) ? k_t : v_t);
                *(float4*)&dst[(size_t)(h * M_ROWS + mm) * D_DIM + daddr] =
                    *(float4*)vals;
            } else {
                float4 o;
                o.x = 1.0f / (1.0f + __expf(-vals[0]));
                o.y = 1.0f / (1.0f + __expf(-vals[1]));
                o.z = 1.0f / (1.0f + __expf(-vals[2]));
                o.w = 1.0f / (1.0f + __expf(-vals[3]));
                *(float4*)&g_t[(size_t)(h * M_ROWS + mm) * D_DIM + daddr] = o;
            }
        }
    }
}

// ---------------- Kernel 3: attention; emits ao as bf16 hi/lo --------------
// b2 bias loads software-pipelined: next js4's 4x float4 issued before the
// current js4's exp/FMA body (hides ~200-400cy L2 latency under ~900cy of
// trans+VALU work). g_t loads hoisted above the DPP reduction block.
__global__ __launch_bounds__(256) void attn_kernel(
    const float* __restrict__ q_t, const float* __restrict__ k_t,
    const float* __restrict__ v_t, const float* __restrict__ g_t,
    const float* __restrict__ b2, unsigned short* __restrict__ ao_hi,
    unsigned short* __restrict__ ao_lo)
{
    __shared__ float k_sh[256][32];
    __shared__ float v_sh[256][32];
    int blk = blockIdx.x;
    int h = blk & 7, s = (blk >> 3) & 7, it = blk >> 6;
    int t = threadIdx.x;
    const float* kb = k_t + (size_t)(h * M_ROWS + s * N_RES) * D_DIM;
    const float* vb = v_t + (size_t)(h * M_ROWS + s * N_RES) * D_DIM;
    for (int idx = t; idx < 2048; idx += 256) {
        ((float4*)k_sh)[idx] = ((const float4*)kb)[idx];
        ((float4*)v_sh)[idx] = ((const float4*)vb)[idx];
    }
    __syncthreads();
    int jp = t & 3, dg = (t >> 2) & 7, li = t >> 5;
    int d0 = dg * 4;
    const float SCL2 = 0.17677669529663687f * LOG2E;
    int ig[4], mrow[4];
    float qs[4][4];
#pragma unroll
    for (int r = 0; r < 4; r++) {
        ig[r] = it * 32 + r * 8 + li;
        mrow[r] = s * N_RES + ig[r];
        float4 q4 = *(const float4*)&q_t[(size_t)(h * M_ROWS + mrow[r]) * D_DIM + d0];
        qs[r][0] = q4.x * SCL2; qs[r][1] = q4.y * SCL2;
        qs[r][2] = q4.z * SCL2; qs[r][3] = q4.w * SCL2;
    }
    float den[4][4] = {}, acc[4][4] = {};
    const float* bbase = b2 + h * 65536;
    float4 bbv[4];
#pragma unroll
    for (int r = 0; r < 4; r++)
        bbv[r] = *(const float4*)&bbase[ig[r] * 256 + jp * 64];
    for (int js4 = 0; js4 < 16; js4++) {
        float bb[4][4];
#pragma unroll
        for (int r = 0; r < 4; r++)
            *(float4*)&bb[r][0] = bbv[r];
        if (js4 < 15) {
#pragma unroll
            for (int r = 0; r < 4; r++)
                bbv[r] = *(const float4*)&bbase[ig[r] * 256 + jp * 64 + (js4 + 1) * 4];
        }
#pragma unroll
        for (int u = 0; u < 4; u++) {
            int j = jp * 64 + js4 * 4 + u;
            float ka[4], va[4];
            *(float4*)ka = *(const float4*)&k_sh[j][d0];
            *(float4*)va = *(const float4*)&v_sh[j][d0];
#pragma unroll
            for (int r = 0; r < 4; r++) {
#pragma unroll
                for (int c = 0; c < 4; c++) {
                    float e = __builtin_amdgcn_exp2f(qs[r][c] * ka[c] + bb[r][u]);
                    den[r][c] += e;
                    acc[r][c] += e * va[c];
                }
            }
        }
    }
    // hoist gate loads so their latency hides under the DPP reductions
    float4 g4[4];
#pragma unroll
    for (int r = 0; r < 4; r++)
        g4[r] = *(const float4*)&g_t[(size_t)(h * M_ROWS + mrow[r]) * D_DIM + d0];
#pragma unroll
    for (int r = 0; r < 4; r++)
#pragma unroll
        for (int c = 0; c < 4; c++) {
            den[r][c] = quad_sum(den[r][c]);
            acc[r][c] = quad_sum(acc[r][c]);
        }
    if (jp == 0) {
#pragma unroll
        for (int r = 0; r < 4; r++) {
            float o[4];
            o[0] = g4[r].x * acc[r][0] * __builtin_amdgcn_rcpf(den[r][0]);
            o[1] = g4[r].y * acc[r][1] * __builtin_amdgcn_rcpf(den[r][1]);
            o[2] = g4[r].z * acc[r][2] * __builtin_amdgcn_rcpf(den[r][2]);
            o[3] = g4[r].w * acc[r][3] * __builtin_amdgcn_rcpf(den[r][3]);
            unsigned short hi[4], lo[4];
#pragma unroll
            for (int c = 0; c < 4; c++) {
                hi[c] = bf16rn(o[c]);
                lo[c] = bf16rn(o[c] - __uint_as_float((unsigned)hi[c] << 16));
            }
            size_t base = (size_t)mrow[r] * 256 + h * 32 + d0;
            uint2 ph, pl;
            ph.x = (unsigned)hi[0] | ((unsigned)hi[1] << 16);
            ph.y = (unsigned)hi[2] | ((unsigned)hi[3] << 16);
            pl.x = (unsigned)lo[0] | ((unsigned)lo[1] << 16);
            pl.y = (unsigned)lo[2] | ((unsigned)lo[3] << 16);
            *(uint2*)&ao_hi[base] = ph;
            *(uint2*)&ao_lo[base] = pl;
        }
    }
}

// ------- Kernel 4: out projection, 16x64 tiles, dbuf single-barrier --------
// grid (4 n, 128 m) = 512 blocks -> 2 blocks/CU (was 1). Double-buffered
// As/Bs: one __syncthreads per r-iter; writes to buf^1 are WAR-safe because
// the barrier at iteration entry retires all prior ds_reads of that buffer.
__global__ __launch_bounds__(256) void out_mfma_kernel(
    const unsigned short* __restrict__ ahi, const unsigned short* __restrict__ alo,
    const unsigned short* __restrict__ whi, const unsigned short* __restrict__ wlo,
    const float* __restrict__ bias, float* __restrict__ out)
{
    __shared__ unsigned short As[2][16 * 72];
    __shared__ unsigned short Bs[2][64 * 72];
    __shared__ float Cs[16 * 68];
    int t = threadIdx.x;
    int n0 = blockIdx.x * 64, m0 = blockIdx.y * 16;
    int w = t >> 6, L = t & 63;
    int wn = w * 16;
    int l15 = L & 15, l4 = L >> 4;
    int alm = t >> 3, alk = (t & 7) * 8;   // A staging: t<128 only
    bool doA = (t < 128);
    floatx4 acc = (floatx4){0, 0, 0, 0};

    short8 pa, pb[2];
    if (doA) pa = *(const short8*)&ahi[(m0 + alm) * 256 + alk];
#pragma unroll
    for (int j = 0; j < 2; j++) {
        int id = t + 256 * j;
        int bn = id >> 3, bc = (id & 7) * 8;
        pb[j] = *(const short8*)&whi[(n0 + bn) * 256 + bc];
    }
    // stage r=0 into buffer 0
    if (doA) *(short8*)&As[0][alm * 72 + alk] = pa;
#pragma unroll
    for (int j = 0; j < 2; j++) {
        int id = t + 256 * j;
        int bn = id >> 3, bc = (id & 7) * 8;
        *(short8*)&Bs[0][bn * 72 + bc] = pb[j];
    }

    for (int r = 0; r < 12; r++) {
        if (r < 11) {
            int rn = r + 1;
            int seg = rn >> 2, kb = (rn & 3) * 64;
            const unsigned short* An = (seg == 1) ? alo : ahi;
            const unsigned short* Bn = (seg == 2) ? wlo : whi;
            if (doA) pa = *(const short8*)&An[(m0 + alm) * 256 + kb + alk];
#pragma unroll
            for (int j = 0; j < 2; j++) {
                int id = t + 256 * j;
                int bn = id >> 3, bc = (id & 7) * 8;
                pb[j] = *(const short8*)&Bn[(n0 + bn) * 256 + kb + bc];
            }
        }
        __syncthreads();
        int cur = r & 1;
#pragma unroll
        for (int ks = 0; ks < 2; ks++) {
            int ko = ks * 32 + l4 * 8;
            short8 af = *(short8*)&As[cur][l15 * 72 + ko];
            short8 bf = *(short8*)&Bs[cur][(wn + l15) * 72 + ko];
            acc = __builtin_amdgcn_mfma_f32_16x16x32_bf16(af, bf, acc, 0, 0, 0);
        }
        if (r < 11) {
            int nxt = cur ^ 1;
            if (doA) *(short8*)&As[nxt][alm * 72 + alk] = pa;
#pragma unroll
            for (int j = 0; j < 2; j++) {
                int id = t + 256 * j;
                int bn = id >> 3, bc = (id & 7) * 8;
                *(short8*)&Bs[nxt][bn * 72 + bc] = pb[j];
            }
        }
    }
#pragma unroll
    for (int rg = 0; rg < 4; rg++)
        Cs[(l4 * 4 + rg) * 68 + wn + l15] = acc[rg];
    __syncthreads();
    {
        int m = t >> 4, nc = (t & 15) * 4;
        float4 v = *(float4*)&Cs[m * 68 + nc];
        float4 bb = *(const float4*)&bias[n0 + nc];
        float4 o;
        o.x = v.x + bb.x; o.y = v.y + bb.y;
        o.z = v.z + bb.z; o.w = v.w + bb.w;
        *(float4*)&out[(size_t)(m0 + m) * 256 + n0 + nc] = o;
    }
}

extern "C" void kernel_launch(void* const* d_in, const int* in_sizes, int n_in,
                              void* d_out, int out_size, void* d_ws, size_t ws_size,
                              hipStream_t stream)
{
    const float* msa_rep   = (const float*)d_in[0];
    const float* pair_rep  = (const float*)d_in[1];
    const float* ln_w      = (const float*)d_in[2];
    const float* ln_b      = (const float*)d_in[3];
    const float* w_qkv     = (const float*)d_in[4];
    const float* ln_pair_w = (const float*)d_in[5];
    const float* ln_pair_b = (const float*)d_in[6];
    const float* w_b       = (const float*)d_in[7];
    const float* w_g       = (const float*)d_in[8];
    const float* w_out     = (const float*)d_in[9];
    const float* b_out     = (const float*)d_in[10];
    float* out = (float*)d_out;

    float* ws = (float*)d_ws;
    const size_t CH = 524288;     // 2048*256 floats
    float* q_t = ws + 0 * CH;
    float* k_t = ws + 1 * CH;
    float* v_t = ws + 2 * CH;
    float* g_t = ws + 3 * CH;
    float* b2  = ws + 4 * CH;
    unsigned short* ao_hi   = (unsigned short*)(ws + 5 * CH);
    unsigned short* ao_lo   = ao_hi + (size_t)M_ROWS * 256;
    unsigned short* xhi     = (unsigned short*)(ws + 6 * CH);
    unsigned short* xlo     = xhi + (size_t)M_ROWS * 256;
    unsigned short* whiT    = (unsigned short*)(ws + 7 * CH);
    unsigned short* wloT    = whiT + (size_t)XW_N * 256;
    unsigned short* wouthiT = (unsigned short*)(ws + 8 * CH);
    unsigned short* woutloT = wouthiT + 65536;

    prep_kernel<<<512, 256, 0, stream>>>(
        w_qkv, w_g, whiT, wloT,
        w_out, wouthiT, woutloT,
        msa_rep, ln_w, ln_b, xhi, xlo);

    mid_kernel<<<1536, 256, 0, stream>>>(
        pair_rep, ln_pair_w, ln_pair_b, w_b, b2,
        xhi, xlo, whiT, wloT, q_t, k_t, v_t, g_t);

    attn_kernel<<<512, 256, 0, stream>>>(q_t, k_t, v_t, g_t, b2, ao_hi, ao_lo);

    out_mfma_kernel<<<dim3(4, 128), 256, 0, stream>>>(
        ao_hi, ao_lo, wouthiT, woutloT, b_out, out);
}

// Round 5
// 141.463 us; speedup vs baseline: 2.1635x; 1.0172x over previous
//
#include <hip/hip_runtime.h>
#include <math.h>

#define S_DIM 8
#define N_RES 256
#define MSA_DIM 256
#define PAIR_DIM 128
#define D_DIM 32
#define H_DIM 8
#define M_ROWS (S_DIM * N_RES)      // 2048
#define QKV_N (3 * H_DIM * D_DIM)   // 768
#define HD (H_DIM * D_DIM)          // 256
#define XW_N 1024                   // qkv(768) + gate(256)
#define LOG2E 1.4426950408889634f

typedef __attribute__((ext_vector_type(8))) short short8;
typedef __attribute__((ext_vector_type(4))) float floatx4;

// ---- wave64 sum via DPP; total lands in lane 63
#define DPP_ADD(x, ctrl, rmask)                                                \
    x += __int_as_float(__builtin_amdgcn_update_dpp(                           \
        0, __float_as_int(x), (ctrl), (rmask), 0xf, true))

__device__ __forceinline__ float wave_sum63(float x) {
    DPP_ADD(x, 0x111, 0xf);
    DPP_ADD(x, 0x112, 0xf);
    DPP_ADD(x, 0x114, 0xf);
    DPP_ADD(x, 0x118, 0xf);
    DPP_ADD(x, 0x142, 0xa);
    DPP_ADD(x, 0x143, 0xc);
    return x;
}

__device__ __forceinline__ float quad_sum(float x) {
    x += __int_as_float(__builtin_amdgcn_update_dpp(
        0, __float_as_int(x), 0xB1, 0xf, 0xf, true));
    x += __int_as_float(__builtin_amdgcn_update_dpp(
        0, __float_as_int(x), 0x4E, 0xf, 0xf, true));
    return x;
}

__device__ __forceinline__ unsigned short bf16rn(float v) {
    unsigned u = __float_as_uint(v);
    return (unsigned short)((u + 0x7FFF + ((u >> 16) & 1)) >> 16);
}

// =========== Kernel 1 "prep": LN(msa) + wconv, 512 compact blocks ==========
__global__ __launch_bounds__(256) void prep_kernel(
    const float* __restrict__ w_qkv, const float* __restrict__ w_g,
    unsigned short* __restrict__ whiT, unsigned short* __restrict__ wloT,
    const float* __restrict__ w_out,
    unsigned short* __restrict__ wouthiT, unsigned short* __restrict__ woutloT,
    const float* __restrict__ msa, const float* __restrict__ lnw,
    const float* __restrict__ lnb, unsigned short* __restrict__ xhi,
    unsigned short* __restrict__ xlo)
{
    int b = blockIdx.x;
    int t = threadIdx.x;

    // ---- LayerNorm: one wave per row, 4 rows/block (rows = b*4+wave) ----
    {
        int wv = t >> 6, l = t & 63;
        int row = b * 4 + wv;
        float4 v4 = *(const float4*)&msa[(size_t)row * 256 + l * 4];
        float s1 = v4.x + v4.y + v4.z + v4.w;
        float s2 = v4.x * v4.x + v4.y * v4.y + v4.z * v4.z + v4.w * v4.w;
        s1 = wave_sum63(s1);
        s2 = wave_sum63(s2);
        float S1 = __int_as_float(__builtin_amdgcn_readlane(__float_as_int(s1), 63));
        float S2 = __int_as_float(__builtin_amdgcn_readlane(__float_as_int(s2), 63));
        float mu = S1 * (1.0f / 256.0f);
        float var = S2 * (1.0f / 256.0f) - mu * mu;
        float rs = rsqrtf(var + 1e-5f);
        float4 w4 = *(const float4*)&lnw[l * 4];
        float4 bb4 = *(const float4*)&lnb[l * 4];
        float y[4];
        y[0] = (v4.x - mu) * rs * w4.x + bb4.x;
        y[1] = (v4.y - mu) * rs * w4.y + bb4.y;
        y[2] = (v4.z - mu) * rs * w4.z + bb4.z;
        y[3] = (v4.w - mu) * rs * w4.w + bb4.w;
        unsigned short hh[4], ll[4];
#pragma unroll
        for (int i = 0; i < 4; i++) {
            hh[i] = bf16rn(y[i]);
            ll[i] = bf16rn(y[i] - __uint_as_float((unsigned)hh[i] << 16));
        }
        uint2 ph, pl;
        ph.x = (unsigned)hh[0] | ((unsigned)hh[1] << 16);
        ph.y = (unsigned)hh[2] | ((unsigned)hh[3] << 16);
        pl.x = (unsigned)ll[0] | ((unsigned)ll[1] << 16);
        pl.y = (unsigned)ll[2] | ((unsigned)ll[3] << 16);
        *(uint2*)&xhi[(size_t)row * 256 + l * 4] = ph;
        *(uint2*)&xlo[(size_t)row * 256 + l * 4] = pl;
    }

    // ---- wconv W = [w_qkv | w_g]: 32768 units = 512 blocks * 64 ----
    if (t < 64) {
        int id = b * 64 + t;
        int n = id >> 5, oct = id & 31, k0 = oct * 8;
        const float* src;
        int stride;
        if (n < QKV_N) { src = w_qkv + n; stride = QKV_N; }
        else           { src = w_g + (n - QKV_N); stride = HD; }
        unsigned short h8[8], l8[8];
#pragma unroll
        for (int j = 0; j < 8; j++) {
            float v = src[(size_t)(k0 + j) * stride];
            unsigned short h = bf16rn(v);
            h8[j] = h;
            l8[j] = bf16rn(v - __uint_as_float((unsigned)h << 16));
        }
        *(short8*)&whiT[n * 256 + k0] = *(short8*)h8;
        *(short8*)&wloT[n * 256 + k0] = *(short8*)l8;
    } else if (t < 80) {
        // wconv w_out (ao-layout row perm): 8192 units = 512 * 16
        int id = b * 16 + (t - 64);
        int n = id >> 5, oct = id & 31, k0 = oct * 8;
        unsigned short h8[8], l8[8];
#pragma unroll
        for (int j = 0; j < 8; j++) {
            int k = k0 + j;
            int wrow = (k & 31) * 8 + (k >> 5);
            float v = w_out[(size_t)wrow * 256 + n];
            unsigned short h = bf16rn(v);
            h8[j] = h;
            l8[j] = bf16rn(v - __uint_as_float((unsigned)h << 16));
        }
        *(short8*)&wouthiT[n * 256 + k0] = *(short8*)h8;
        *(short8*)&woutloT[n * 256 + k0] = *(short8*)l8;
    }
}

// ====== Kernel 2 "mid": pair_bias (1024 blocks) || xw GEMM (512 blocks) ====
// GEMM restructured kb-outer: per K-segment stage {Ahi,Alo,Bhi,Blo} ONCE
// (36 KB LDS), then 3 bf16x3 passes (24 MFMA/wave) from LDS. Barriers/block
// 24 -> 8; global staging 192 -> 128 KB/block; next-segment regs prefetched
// under the MFMA block.
__global__ __launch_bounds__(256) void mid_kernel(
    const float* __restrict__ pair, const float* __restrict__ lw,
    const float* __restrict__ lb, const float* __restrict__ wb,
    float* __restrict__ b2,
    const unsigned short* __restrict__ xhi, const unsigned short* __restrict__ xlo,
    const unsigned short* __restrict__ whiT, const unsigned short* __restrict__ wloT,
    float* __restrict__ q_t, float* __restrict__ k_t,
    float* __restrict__ v_t, float* __restrict__ g_t)
{
    __shared__ __align__(16) char smem[54272];  // GEMM 4x9216 + Cs 17408; pair 8320
    int bx = blockIdx.x;
    int t = threadIdx.x;
    int g3 = bx / 3, r3 = bx - g3 * 3;

    if (r3 != 2) {
        // ---------------- pair_bias ----------------
        float* As = (float*)smem;
        float* Spart = (float*)smem + 1552;
        float* Qpart = (float*)smem + 1816;
        int pair_id = g3 * 2 + r3;            // [0,1024)
        if (t < 128) {
            float lwc = lw[t];
#pragma unroll
            for (int h = 0; h < 8; h++)
                As[t * 12 + h] = lwc * wb[t * 8 + h] * LOG2E;
        }
        __syncthreads();
        {
            int h = t >> 5, seg = t & 31, cbase = seg * 4;
            float sa = 0, sq = 0;
#pragma unroll
            for (int cc = 0; cc < 4; cc++) {
                int c = cbase + cc;
                sa += As[c * 12 + h];
                sq += lb[c] * wb[c * 8 + h];
            }
            Spart[h * 33 + seg] = sa;
            Qpart[h * 33 + seg] = sq * LOG2E;
        }
        __syncthreads();
        if (t < 8) {
            float s = 0, q = 0;
#pragma unroll
            for (int j = 0; j < 32; j++) {
                s += Spart[t * 33 + j];
                q += Qpart[t * 33 + j];
            }
            As[1536 + t] = s;
            As[1544 + t] = q;
        }
        __syncthreads();
        int row = pair_id * 64 + (t >> 2);
        int q = t & 3;
        const float* in = pair + (size_t)row * PAIR_DIM;
        float4 x4[8];
#pragma unroll
        for (int it = 0; it < 8; it++)
            x4[it] = *(const float4*)&in[it * 16 + q * 4];
        float s = 0, s2 = 0;
        float dot[8] = {};
#pragma unroll
        for (int it = 0; it < 8; it++) {
            float xk[4];
            *(float4*)xk = x4[it];
#pragma unroll
            for (int k = 0; k < 4; k++) {
                int c = it * 16 + q * 4 + k;
                float xv = xk[k];
                s += xv; s2 += xv * xv;
                float4 A0 = *(const float4*)&As[c * 12];
                float4 A1 = *(const float4*)&As[c * 12 + 4];
                dot[0] += xv * A0.x; dot[1] += xv * A0.y;
                dot[2] += xv * A0.z; dot[3] += xv * A0.w;
                dot[4] += xv * A1.x; dot[5] += xv * A1.y;
                dot[6] += xv * A1.z; dot[7] += xv * A1.w;
            }
        }
        s = quad_sum(s);
        s2 = quad_sum(s2);
#pragma unroll
        for (int h = 0; h < 8; h++) dot[h] = quad_sum(dot[h]);
        float mu = s * (1.0f / 128.0f);
        float var = s2 * (1.0f / 128.0f) - mu * mu;
        float rs = rsqrtf(var + 1e-5f);
        int h0 = q * 2;
#pragma unroll
        for (int u = 0; u < 2; u++) {
            int h = h0 + u;
            b2[h * 65536 + row] = rs * (dot[h] - mu * As[1536 + h]) + As[1544 + h];
        }
    } else {
        // ---------------- xw GEMM, 64x64 tile, kb-outer ----------------
        unsigned short* Ahi = (unsigned short*)smem;       // 64*72 each
        unsigned short* Alo = Ahi + 64 * 72;
        unsigned short* Bhi = Alo + 64 * 72;
        unsigned short* Blo = Bhi + 64 * 72;
        float* Cs = (float*)(smem + 4 * 9216);             // 64*68 floats
        int gid = g3;                                      // [0,512)
        int n0 = (gid & 15) * 64, m0 = (gid >> 4) * 64;
        int w = t >> 6, L = t & 63;
        int wm = (w & 1) * 32, wn = (w >> 1) * 32;
        int l15 = L & 15, l4 = L >> 4;
        int am = t >> 3, ak = (t & 7) * 8;                 // staging coords
        int bn0 = t >> 3, bn1 = (t + 256) >> 3;
        int bc = (t & 7) * 8;
        floatx4 acc[2][2];
#pragma unroll
        for (int a = 0; a < 2; a++)
#pragma unroll
            for (int c = 0; c < 2; c++) acc[a][c] = (floatx4){0, 0, 0, 0};

        // prologue: load kb=0 registers
        short8 rahi0 = *(const short8*)&xhi[(m0 + am) * 256 + ak];
        short8 rahi1 = *(const short8*)&xhi[(m0 + am + 32) * 256 + ak];
        short8 ralo0 = *(const short8*)&xlo[(m0 + am) * 256 + ak];
        short8 ralo1 = *(const short8*)&xlo[(m0 + am + 32) * 256 + ak];
        short8 rbhi0 = *(const short8*)&whiT[(n0 + bn0) * 256 + bc];
        short8 rbhi1 = *(const short8*)&whiT[(n0 + bn1) * 256 + bc];
        short8 rblo0 = *(const short8*)&wloT[(n0 + bn0) * 256 + bc];
        short8 rblo1 = *(const short8*)&wloT[(n0 + bn1) * 256 + bc];

        for (int kb = 0; kb < 4; kb++) {
            __syncthreads();   // WAR: prior segment's frag reads retired
            *(short8*)&Ahi[am * 72 + ak] = rahi0;
            *(short8*)&Ahi[(am + 32) * 72 + ak] = rahi1;
            *(short8*)&Alo[am * 72 + ak] = ralo0;
            *(short8*)&Alo[(am + 32) * 72 + ak] = ralo1;
            *(short8*)&Bhi[bn0 * 72 + bc] = rbhi0;
            *(short8*)&Bhi[bn1 * 72 + bc] = rbhi1;
            *(short8*)&Blo[bn0 * 72 + bc] = rblo0;
            *(short8*)&Blo[bn1 * 72 + bc] = rblo1;
            __syncthreads();
            if (kb < 3) {
                int kB = (kb + 1) * 64;
                rahi0 = *(const short8*)&xhi[(m0 + am) * 256 + kB + ak];
                rahi1 = *(const short8*)&xhi[(m0 + am + 32) * 256 + kB + ak];
                ralo0 = *(const short8*)&xlo[(m0 + am) * 256 + kB + ak];
                ralo1 = *(const short8*)&xlo[(m0 + am + 32) * 256 + kB + ak];
                rbhi0 = *(const short8*)&whiT[(n0 + bn0) * 256 + kB + bc];
                rbhi1 = *(const short8*)&whiT[(n0 + bn1) * 256 + kB + bc];
                rblo0 = *(const short8*)&wloT[(n0 + bn0) * 256 + kB + bc];
                rblo1 = *(const short8*)&wloT[(n0 + bn1) * 256 + kB + bc];
            }
            // 3 bf16x3 passes: hi*hi, lo*hi, hi*lo
#pragma unroll
            for (int pass = 0; pass < 3; pass++) {
                const unsigned short* Ab = (pass == 1) ? Alo : Ahi;
                const unsigned short* Bb = (pass == 2) ? Blo : Bhi;
#pragma unroll
                for (int ks = 0; ks < 2; ks++) {
                    int ko = ks * 32 + l4 * 8;
                    short8 af[2], bf[2];
#pragma unroll
                    for (int a = 0; a < 2; a++)
                        af[a] = *(short8*)&Ab[(wm + a * 16 + l15) * 72 + ko];
#pragma unroll
                    for (int c = 0; c < 2; c++)
                        bf[c] = *(short8*)&Bb[(wn + c * 16 + l15) * 72 + ko];
#pragma unroll
                    for (int a = 0; a < 2; a++)
#pragma unroll
                        for (int c = 0; c < 2; c++)
                            acc[a][c] = __builtin_amdgcn_mfma_f32_16x16x32_bf16(
                                af[a], bf[c], acc[a][c], 0, 0, 0);
                }
            }
        }
#pragma unroll
        for (int a = 0; a < 2; a++)
#pragma unroll
            for (int c = 0; c < 2; c++) {
                int nl = wn + c * 16 + l15;
#pragma unroll
                for (int rg = 0; rg < 4; rg++) {
                    int ml = wm + a * 16 + l4 * 4 + rg;
                    Cs[ml * 68 + nl] = acc[a][c][rg];
                }
            }
        __syncthreads();
        int qkv_mode = (n0 < QKV_N);
        int chunk = n0 >> 8;
        int dbase = (n0 & 255) >> 3;
#pragma unroll
        for (int j = 0; j < 4; j++) {
            int id = t + 256 * j;             // [0,1024)
            int m = id >> 4;
            int h = (id >> 1) & 7;
            int dq = id & 1;
            float vals[4];
#pragma unroll
            for (int jj = 0; jj < 4; jj++)
                vals[jj] = Cs[m * 68 + (dq * 4 + jj) * 8 + h];
            int mm = m0 + m;
            int daddr = dbase + dq * 4;
            if (qkv_mode) {
                float* dst = (chunk == 0) ? q_t : ((chunk == 1) ? k_t : v_t);
                *(float4*)&dst[(size_t)(h * M_ROWS + mm) * D_DIM + daddr] =
                    *(float4*)vals;
            } else {
                float4 o;
                o.x = 1.0f / (1.0f + __expf(-vals[0]));
                o.y = 1.0f / (1.0f + __expf(-vals[1]));
                o.z = 1.0f / (1.0f + __expf(-vals[2]));
                o.w = 1.0f / (1.0f + __expf(-vals[3]));
                *(float4*)&g_t[(size_t)(h * M_ROWS + mm) * D_DIM + daddr] = o;
            }
        }
    }
}

// ---------------- Kernel 3: attention; emits ao as bf16 hi/lo --------------
// b2 bias loads software-pipelined; g_t loads hoisted above the reduction.
__global__ __launch_bounds__(256) void attn_kernel(
    const float* __restrict__ q_t, const float* __restrict__ k_t,
    const float* __restrict__ v_t, const float* __restrict__ g_t,
    const float* __restrict__ b2, unsigned short* __restrict__ ao_hi,
    unsigned short* __restrict__ ao_lo)
{
    __shared__ float k_sh[256][32];
    __shared__ float v_sh[256][32];
    int blk = blockIdx.x;
    int h = blk & 7, s = (blk >> 3) & 7, it = blk >> 6;
    int t = threadIdx.x;
    const float* kb = k_t + (size_t)(h * M_ROWS + s * N_RES) * D_DIM;
    const float* vb = v_t + (size_t)(h * M_ROWS + s * N_RES) * D_DIM;
    for (int idx = t; idx < 2048; idx += 256) {
        ((float4*)k_sh)[idx] = ((const float4*)kb)[idx];
        ((float4*)v_sh)[idx] = ((const float4*)vb)[idx];
    }
    __syncthreads();
    int jp = t & 3, dg = (t >> 2) & 7, li = t >> 5;
    int d0 = dg * 4;
    const float SCL2 = 0.17677669529663687f * LOG2E;
    int ig[4], mrow[4];
    float qs[4][4];
#pragma unroll
    for (int r = 0; r < 4; r++) {
        ig[r] = it * 32 + r * 8 + li;
        mrow[r] = s * N_RES + ig[r];
        float4 q4 = *(const float4*)&q_t[(size_t)(h * M_ROWS + mrow[r]) * D_DIM + d0];
        qs[r][0] = q4.x * SCL2; qs[r][1] = q4.y * SCL2;
        qs[r][2] = q4.z * SCL2; qs[r][3] = q4.w * SCL2;
    }
    float den[4][4] = {}, acc[4][4] = {};
    const float* bbase = b2 + h * 65536;
    float4 bbv[4];
#pragma unroll
    for (int r = 0; r < 4; r++)
        bbv[r] = *(const float4*)&bbase[ig[r] * 256 + jp * 64];
    for (int js4 = 0; js4 < 16; js4++) {
        float bb[4][4];
#pragma unroll
        for (int r = 0; r < 4; r++)
            *(float4*)&bb[r][0] = bbv[r];
        if (js4 < 15) {
#pragma unroll
            for (int r = 0; r < 4; r++)
                bbv[r] = *(const float4*)&bbase[ig[r] * 256 + jp * 64 + (js4 + 1) * 4];
        }
#pragma unroll
        for (int u = 0; u < 4; u++) {
            int j = jp * 64 + js4 * 4 + u;
            float ka[4], va[4];
            *(float4*)ka = *(const float4*)&k_sh[j][d0];
            *(float4*)va = *(const float4*)&v_sh[j][d0];
#pragma unroll
            for (int r = 0; r < 4; r++) {
#pragma unroll
                for (int c = 0; c < 4; c++) {
                    float e = __builtin_amdgcn_exp2f(qs[r][c] * ka[c] + bb[r][u]);
                    den[r][c] += e;
                    acc[r][c] += e * va[c];
                }
            }
        }
    }
    // hoist gate loads so their latency hides under the DPP reductions
    float4 g4[4];
#pragma unroll
    for (int r = 0; r < 4; r++)
        g4[r] = *(const float4*)&g_t[(size_t)(h * M_ROWS + mrow[r]) * D_DIM + d0];
#pragma unroll
    for (int r = 0; r < 4; r++)
#pragma unroll
        for (int c = 0; c < 4; c++) {
            den[r][c] = quad_sum(den[r][c]);
            acc[r][c] = quad_sum(acc[r][c]);
        }
    if (jp == 0) {
#pragma unroll
        for (int r = 0; r < 4; r++) {
            float o[4];
            o[0] = g4[r].x * acc[r][0] * __builtin_amdgcn_rcpf(den[r][0]);
            o[1] = g4[r].y * acc[r][1] * __builtin_amdgcn_rcpf(den[r][1]);
            o[2] = g4[r].z * acc[r][2] * __builtin_amdgcn_rcpf(den[r][2]);
            o[3] = g4[r].w * acc[r][3] * __builtin_amdgcn_rcpf(den[r][3]);
            unsigned short hi[4], lo[4];
#pragma unroll
            for (int c = 0; c < 4; c++) {
                hi[c] = bf16rn(o[c]);
                lo[c] = bf16rn(o[c] - __uint_as_float((unsigned)hi[c] << 16));
            }
            size_t base = (size_t)mrow[r] * 256 + h * 32 + d0;
            uint2 ph, pl;
            ph.x = (unsigned)hi[0] | ((unsigned)hi[1] << 16);
            ph.y = (unsigned)hi[2] | ((unsigned)hi[3] << 16);
            pl.x = (unsigned)lo[0] | ((unsigned)lo[1] << 16);
            pl.y = (unsigned)lo[2] | ((unsigned)lo[3] << 16);
            *(uint2*)&ao_hi[base] = ph;
            *(uint2*)&ao_lo[base] = pl;
        }
    }
}

// ------- Kernel 4: out projection, 16x64 tiles, dbuf single-barrier --------
__global__ __launch_bounds__(256) void out_mfma_kernel(
    const unsigned short* __restrict__ ahi, const unsigned short* __restrict__ alo,
    const unsigned short* __restrict__ whi, const unsigned short* __restrict__ wlo,
    const float* __restrict__ bias, float* __restrict__ out)
{
    __shared__ unsigned short As[2][16 * 72];
    __shared__ unsigned short Bs[2][64 * 72];
    __shared__ float Cs[16 * 68];
    int t = threadIdx.x;
    int n0 = blockIdx.x * 64, m0 = blockIdx.y * 16;
    int w = t >> 6, L = t & 63;
    int wn = w * 16;
    int l15 = L & 15, l4 = L >> 4;
    int alm = t >> 3, alk = (t & 7) * 8;   // A staging: t<128 only
    bool doA = (t < 128);
    floatx4 acc = (floatx4){0, 0, 0, 0};

    short8 pa, pb[2];
    if (doA) pa = *(const short8*)&ahi[(m0 + alm) * 256 + alk];
#pragma unroll
    for (int j = 0; j < 2; j++) {
        int id = t + 256 * j;
        int bn = id >> 3, bc = (id & 7) * 8;
        pb[j] = *(const short8*)&whi[(n0 + bn) * 256 + bc];
    }
    // stage r=0 into buffer 0
    if (doA) *(short8*)&As[0][alm * 72 + alk] = pa;
#pragma unroll
    for (int j = 0; j < 2; j++) {
        int id = t + 256 * j;
        int bn = id >> 3, bc = (id & 7) * 8;
        *(short8*)&Bs[0][bn * 72 + bc] = pb[j];
    }

    for (int r = 0; r < 12; r++) {
        if (r < 11) {
            int rn = r + 1;
            int seg = rn >> 2, kb = (rn & 3) * 64;
            const unsigned short* An = (seg == 1) ? alo : ahi;
            const unsigned short* Bn = (seg == 2) ? wlo : whi;
            if (doA) pa = *(const short8*)&An[(m0 + alm) * 256 + kb + alk];
#pragma unroll
            for (int j = 0; j < 2; j++) {
                int id = t + 256 * j;
                int bn = id >> 3, bc = (id & 7) * 8;
                pb[j] = *(const short8*)&Bn[(n0 + bn) * 256 + kb + bc];
            }
        }
        __syncthreads();
        int cur = r & 1;
#pragma unroll
        for (int ks = 0; ks < 2; ks++) {
            int ko = ks * 32 + l4 * 8;
            short8 af = *(short8*)&As[cur][l15 * 72 + ko];
            short8 bf = *(short8*)&Bs[cur][(wn + l15) * 72 + ko];
            acc = __builtin_amdgcn_mfma_f32_16x16x32_bf16(af, bf, acc, 0, 0, 0);
        }
        if (r < 11) {
            int nxt = cur ^ 1;
            if (doA) *(short8*)&As[nxt][alm * 72 + alk] = pa;
#pragma unroll
            for (int j = 0; j < 2; j++) {
                int id = t + 256 * j;
                int bn = id >> 3, bc = (id & 7) * 8;
                *(short8*)&Bs[nxt][bn * 72 + bc] = pb[j];
            }
        }
    }
#pragma unroll
    for (int rg = 0; rg < 4; rg++)
        Cs[(l4 * 4 + rg) * 68 + wn + l15] = acc[rg];
    __syncthreads();
    {
        int m = t >> 4, nc = (t & 15) * 4;
        float4 v = *(float4*)&Cs[m * 68 + nc];
        float4 bb = *(const float4*)&bias[n0 + nc];
        float4 o;
        o.x = v.x + bb.x; o.y = v.y + bb.y;
        o.z = v.z + bb.z; o.w = v.w + bb.w;
        *(float4*)&out[(size_t)(m0 + m) * 256 + n0 + nc] = o;
    }
}

extern "C" void kernel_launch(void* const* d_in, const int* in_sizes, int n_in,
                              void* d_out, int out_size, void* d_ws, size_t ws_size,
                              hipStream_t stream)
{
    const float* msa_rep   = (const float*)d_in[0];
    const float* pair_rep  = (const float*)d_in[1];
    const float* ln_w      = (const float*)d_in[2];
    const float* ln_b      = (const float*)d_in[3];
    const float* w_qkv     = (const float*)d_in[4];
    const float* ln_pair_w = (const float*)d_in[5];
    const float* ln_pair_b = (const float*)d_in[6];
    const float* w_b       = (const float*)d_in[7];
    const float* w_g       = (const float*)d_in[8];
    const float* w_out     = (const float*)d_in[9];
    const float* b_out     = (const float*)d_in[10];
    float* out = (float*)d_out;

    float* ws = (float*)d_ws;
    const size_t CH = 524288;     // 2048*256 floats
    float* q_t = ws + 0 * CH;
    float* k_t = ws + 1 * CH;
    float* v_t = ws + 2 * CH;
    float* g_t = ws + 3 * CH;
    float* b2  = ws + 4 * CH;
    unsigned short* ao_hi   = (unsigned short*)(ws + 5 * CH);
    unsigned short* ao_lo   = ao_hi + (size_t)M_ROWS * 256;
    unsigned short* xhi     = (unsigned short*)(ws + 6 * CH);
    unsigned short* xlo     = xhi + (size_t)M_ROWS * 256;
    unsigned short* whiT    = (unsigned short*)(ws + 7 * CH);
    unsigned short* wloT    = whiT + (size_t)XW_N * 256;
    unsigned short* wouthiT = (unsigned short*)(ws + 8 * CH);
    unsigned short* woutloT = wouthiT + 65536;

    prep_kernel<<<512, 256, 0, stream>>>(
        w_qkv, w_g, whiT, wloT,
        w_out, wouthiT, woutloT,
        msa_rep, ln_w, ln_b, xhi, xlo);

    mid_kernel<<<1536, 256, 0, stream>>>(
        pair_rep, ln_pair_w, ln_pair_b, w_b, b2,
        xhi, xlo, whiT, wloT, q_t, k_t, v_t, g_t);

    attn_kernel<<<512, 256, 0, stream>>>(q_t, k_t, v_t, g_t, b2, ao_hi, ao_lo);

    out_mfma_kernel<<<dim3(4, 128), 256, 0, stream>>>(
        ao_hi, ao_lo, wouthiT, woutloT, b_out, out);
}